// Round 3
// baseline (7531.952 us; speedup 1.0000x reference)
//
#include <hip/hip_runtime.h>
#include <math.h>

// Problem constants (reference: B,T,V,E,H = 32,512,32000,300,256)
#define BB 32
#define TT_LEN 512
#define EE 300
#define HH 256
#define G4 1024          // 4*H
#define CMAX 155         // int(round(0.3*512))+1
#define BUDGET 154       // round(0.3*512)
#define TRANS_T 10.0f    // TRANSITION/TEMP
#define NEGF -1.0e9f
#define INV_TEMP 100.0f  // 1/TEMP
#define AST_STRIDE 160   // padded CMAX

typedef _Float16 half2v __attribute__((ext_vector_type(2)));

__device__ __forceinline__ float la(float x, float y) {
  float m = fmaxf(x, y);
  float d = fminf(x, y) - m;
  return m + log1pf(__expf(d));
}

__device__ __forceinline__ float sigm(float x) {
  return 1.0f / (1.0f + __expf(-x));
}

__device__ __forceinline__ float dot2acc(unsigned int wd, unsigned int hd, float acc) {
#if __has_builtin(__builtin_amdgcn_fdot2)
  return __builtin_amdgcn_fdot2(__builtin_bit_cast(half2v, wd),
                                __builtin_bit_cast(half2v, hd), acc, false);
#else
  half2v a = __builtin_bit_cast(half2v, wd);
  half2v b = __builtin_bit_cast(half2v, hd);
  return acc + (float)a.x * (float)b.x + (float)a.y * (float)b.y;
#endif
}

// ---------------- K0: weight prep ------------------------------------------
// wi_p: fp32, [dir][k][j'] with j' = u*4+g (gate interleave)
// wh_hp: f16, blocked for lstm_rec4: [dir][sub][kc][gl][8]
//   global gate = sub*256+gl, k = kc*8+jj; each (dir,sub) slice is a
//   contiguous 128 KB chunk the owning block vector-copies into LDS.
// Also zeroes the 256 sync flags (d_ws is poisoned 0xAA before every launch).
__global__ void prep_weights(const float* wi_f, const float* wi_b,
                             const float* wh_f, const float* wh_b,
                             const float* b_f, const float* b_b,
                             float* wi_p, float* b_p, _Float16* wh_hp,
                             int* flags) {
  int idx = blockIdx.x * blockDim.x + threadIdx.x;
  int stride = gridDim.x * blockDim.x;
  for (int i = idx; i < 2 * EE * G4; i += stride) {
    int dir = i / (EE * G4);
    int r = (i / G4) % EE;
    int j = i % G4;
    int g = j & 3, u = j >> 2;
    const float* src = dir ? wi_b : wi_f;
    wi_p[i] = src[r * G4 + g * HH + u];
  }
  for (int i = idx; i < 2 * HH * G4; i += stride) {
    int jj = i & 7;
    int gl = (i >> 3) & 255;
    int kc = (i >> 11) & 31;
    int sub = (i >> 16) & 3;
    int dir = i >> 18;
    int jg = sub * 256 + gl;       // global permuted gate index
    int g = jg & 3, u = jg >> 2;
    int k = kc * 8 + jj;
    const float* src = dir ? wh_b : wh_f;
    wh_hp[i] = (_Float16)src[k * G4 + g * HH + u];
  }
  for (int i = idx; i < 2 * G4; i += stride) {
    int dir = i / G4;
    int j = i % G4;
    int g = j & 3, u = j >> 2;
    const float* src = dir ? b_b : b_f;
    b_p[i] = src[g * HH + u];
  }
  for (int i = idx; i < 256; i += stride) flags[i] = 0;
}

// ---------------- K_emb: gather embedding rows into dense (B*T, E) ---------
__global__ void gather_emb(const int* x, const float* embed, float* emb_dense) {
  int row = blockIdx.x;
  int v = x[row];
  const float* src = embed + (size_t)v * EE;
  float* dst = emb_dense + (size_t)row * EE;
  for (int k = threadIdx.x; k < EE; k += blockDim.x) dst[k] = src[k];
}

// ---------------- K1: xg = emb @ Wi_perm + b_perm  (fp32 tiled GEMM) -------
#define BM 64
#define BN 64
#define BK 60
__global__ __launch_bounds__(256) void xg_gemm(const float* __restrict__ emb,
                                               const float* __restrict__ wi_p,
                                               const float* __restrict__ b_p,
                                               float* __restrict__ xg) {
  __shared__ float As[BK][68];
  __shared__ float Bs[BK][BN];
  int dir = blockIdx.z;
  int row0 = blockIdx.y * BM;
  int col0 = blockIdx.x * BN;
  const float* Wsrc = wi_p + (size_t)dir * EE * G4;
  int tid = threadIdx.x;
  int ty = tid >> 4, tx = tid & 15;
  float acc[4][4] = {};
  for (int k0 = 0; k0 < EE; k0 += BK) {
    for (int e = tid; e < BM * BK; e += 256) {
      int m = e / BK, k = e % BK;
      As[k][m] = emb[(size_t)(row0 + m) * EE + k0 + k];
    }
    for (int e = tid; e < BK * BN; e += 256) {
      int k = e >> 6, n = e & 63;
      Bs[k][n] = Wsrc[(size_t)(k0 + k) * G4 + col0 + n];
    }
    __syncthreads();
#pragma unroll 4
    for (int k = 0; k < BK; ++k) {
      float4 a = *(const float4*)&As[k][ty << 2];
      float4 b4 = *(const float4*)&Bs[k][tx << 2];
      acc[0][0] += a.x * b4.x; acc[0][1] += a.x * b4.y; acc[0][2] += a.x * b4.z; acc[0][3] += a.x * b4.w;
      acc[1][0] += a.y * b4.x; acc[1][1] += a.y * b4.y; acc[1][2] += a.y * b4.z; acc[1][3] += a.y * b4.w;
      acc[2][0] += a.z * b4.x; acc[2][1] += a.z * b4.y; acc[2][2] += a.z * b4.z; acc[2][3] += a.z * b4.w;
      acc[3][0] += a.w * b4.x; acc[3][1] += a.w * b4.y; acc[3][2] += a.w * b4.z; acc[3][3] += a.w * b4.w;
    }
    __syncthreads();
  }
  float4 bias = *(const float4*)&b_p[dir * G4 + col0 + (tx << 2)];
#pragma unroll
  for (int i = 0; i < 4; ++i) {
    float4 o;
    o.x = acc[i][0] + bias.x;
    o.y = acc[i][1] + bias.y;
    o.z = acc[i][2] + bias.z;
    o.w = acc[i][3] + bias.w;
    *(float4*)&xg[(size_t)(dir * (BB * TT_LEN) + row0 + (ty << 2) + i) * G4 + col0 + (tx << 2)] = o;
  }
}

// ---------------- K2: LSTM recurrence, 4 blocks per (dir,b) ----------------
// Block bid: group = bid&63 (= dir*32+b), sub = bid>>6. Each block owns 64
// hidden units (256 gate outputs), 128 KB f16 weight slice in LDS, exchanges
// its 64 h values (32 packed-f16 dwords) with 3 peers per step.
// Protocol (race-fixed vs round 2):
//   - hxchg is DOUBLE-BUFFERED by step parity. Buffer p is rewritten at
//     step s+2 only after our poll at s+1 saw peer flag >= s+2, which the
//     peer publishes only after its step-s reads drained (pre-barrier
//     s_waitcnt) -> no overwrite race.
//   - payload uses RELAXED AGENT atomics (coherent point, bypasses stale
//     L1/L2); ordering via RELEASE flag store (wave-level vmcnt drain
//     covers the lane stores) + explicit agent ACQUIRE fence after poll.
// Grid = 256 = CU count, 1 block/CU -> all co-resident -> spin-sync safe.
__global__ __launch_bounds__(256, 1) void lstm_rec4(
    const float* __restrict__ xg, const _Float16* __restrict__ wh_hp,
    const float* __restrict__ w_out, float* __restrict__ scores_p4,
    unsigned int* hxchg, int* flags) {
  int bid = blockIdx.x;
  int group = bid & 63;
  int sub = bid >> 6;
  int dir = group >> 5, b = group & 31;
  int tid = threadIdx.x;

  __shared__ uint4 whs4[32 * 256];      // 128 KB: [kc][gate_local], 8 f16 k's
  __shared__ unsigned int hpk[128];     // 256 h as packed f16 pairs, unit-major
  __shared__ float gates[256];

  const uint4* wsrc = (const uint4*)wh_hp + (size_t)(dir * 4 + sub) * 8192;
  for (int i = tid; i < 8192; i += 256) whs4[i] = wsrc[i];
  if (tid < 128) hpk[tid] = 0;
  __syncthreads();

  const float* xgbase =
      xg + (size_t)(dir * (BB * TT_LEN) + b * TT_LEN) * G4 + sub * 256 + tid;
  float wo = 0.0f;
  if (tid < 64) wo = w_out[dir * HH + sub * 64 + tid];
  float cstate = 0.0f;

  int t0 = dir ? (TT_LEN - 1) : 0;
  float xg_next = xgbase[(size_t)t0 * G4];

#pragma unroll 1
  for (int s = 0; s < TT_LEN; ++s) {
    int t = dir ? (TT_LEN - 1 - s) : s;
    float acc = xg_next;
    if (s + 1 < TT_LEN) {
      int t2 = dir ? (TT_LEN - 2 - s) : (s + 1);
      xg_next = xgbase[(size_t)t2 * G4];
    }
#pragma unroll
    for (int c = 0; c < 2; ++c) {
      uint4 hr[16];
#pragma unroll
      for (int i = 0; i < 16; ++i) hr[i] = ((const uint4*)hpk)[c * 16 + i];
#pragma unroll
      for (int kk = 0; kk < 16; ++kk) {
        uint4 w = whs4[(c * 16 + kk) * 256 + tid];
        uint4 h = hr[kk];
        acc = dot2acc(w.x, h.x, acc);
        acc = dot2acc(w.y, h.y, acc);
        acc = dot2acc(w.z, h.z, acc);
        acc = dot2acc(w.w, h.w, acc);
      }
    }
    gates[tid] = acc;
    __syncthreads();

    int par = s & 1;
    if (tid < 64) {
      float4 g4 = ((const float4*)gates)[tid];
      float ig = sigm(g4.x);
      float fg = sigm(g4.y);
      float gg = tanhf(g4.z);
      float og = sigm(g4.w);
      cstate = fg * cstate + ig * gg;
      float h = og * tanhf(cstate);
      float prod = h * wo;
#pragma unroll
      for (int off = 32; off > 0; off >>= 1) prod += __shfl_down(prod, off, 64);
      if (tid == 0) scores_p4[(size_t)bid * TT_LEN + t] = prod;
      float hn = __shfl_down(h, 1, 64);
      if (!(tid & 1)) {
        half2v hp;
        hp.x = (_Float16)h;
        hp.y = (_Float16)hn;
        unsigned int d = __builtin_bit_cast(unsigned int, hp);
        hpk[sub * 32 + (tid >> 1)] = d;
        __hip_atomic_store(&hxchg[((size_t)par * 256 + bid) * 32 + (tid >> 1)], d,
                           __ATOMIC_RELAXED, __HIP_MEMORY_SCOPE_AGENT);
      }
    }
    // publish: RELEASE drains wave0's vmcnt (covers all lane stores above)
    if (tid == 0)
      __hip_atomic_store(&flags[bid], s + 1, __ATOMIC_RELEASE,
                         __HIP_MEMORY_SCOPE_AGENT);
    // poll peers (relaxed spin; acquire fence below orders the data loads)
    if (tid < 96 && (tid & 31) == 0) {
      int p = tid >> 5;
      int peer_sub = (sub + 1 + p) & 3;
      int pbid = peer_sub * 64 + group;
      while (__hip_atomic_load(&flags[pbid], __ATOMIC_RELAXED,
                               __HIP_MEMORY_SCOPE_AGENT) < s + 1) {
      }
    }
    __builtin_amdgcn_fence(__ATOMIC_ACQUIRE, "agent");
    __syncthreads();
    if (tid < 96) {
      int p = tid >> 5;
      int peer_sub = (sub + 1 + p) & 3;
      int pbid = peer_sub * 64 + group;
      int w = tid & 31;
      unsigned int d =
          __hip_atomic_load(&hxchg[((size_t)par * 256 + pbid) * 32 + w],
                            __ATOMIC_RELAXED, __HIP_MEMORY_SCOPE_AGENT);
      hpk[peer_sub * 32 + w] = d;
    }
    __syncthreads();
  }
}

// ---------------- K3: u0 = (sum of 8 score partials + b_out) / TEMP --------
__global__ void combine_scores(const float* __restrict__ scores_p4,
                               const float* __restrict__ b_out,
                               float* __restrict__ u0) {
  int i = blockIdx.x * blockDim.x + threadIdx.x;
  if (i < BB * TT_LEN) {
    int b = i >> 9, t = i & 511;
    float s = b_out[0];
#pragma unroll
    for (int dir = 0; dir < 2; ++dir)
#pragma unroll
      for (int sub = 0; sub < 4; ++sub)
        s += scores_p4[(size_t)(sub * 64 + dir * 32 + b) * TT_LEN + t];
    u0[i] = s * INV_TEMP;
  }
}

// ---------------- K4: CRF forward-backward marginals -----------------------
__global__ __launch_bounds__(192) void dp_kernel(const float* __restrict__ u0all,
                                                 float* __restrict__ alpha_store,
                                                 float* __restrict__ out) {
  int b = blockIdx.x;
  int c = threadIdx.x;
  int lane = c & 63, wid = c >> 6;
  const float* u0 = u0all + b * TT_LEN;
  float* ast = alpha_store + (size_t)b * TT_LEN * AST_STRIDE;
  __shared__ float s0[2][AST_STRIDE], s1[2][AST_STRIDE];
  __shared__ float part[2][4];
  __shared__ float smax[4], ssum[4];

  s0[0][c] = NEGF; s0[1][c] = NEGF; s1[0][c] = NEGF; s1[1][c] = NEGF;
  if (c == 1) s0[0][1] = u0[0] + TRANS_T;
  if (c == 0) s1[0][0] = 0.0f;
  if (c < CMAX) ast[c] = s0[0][c];
  __syncthreads();
  int p = 0;
#pragma unroll 1
  for (int t = 1; t < TT_LEN; ++t) {
    float u0t = u0[t];
    if (c < CMAX) {
      float am0 = (c >= 1) ? s0[p][c - 1] : NEGF;
      float am1 = (c >= 1) ? s1[p][c - 1] : NEGF;
      float n0 = u0t + la(am0 + TRANS_T, am1);
      float n1 = la(s0[p][c], s1[p][c]);
      s0[p ^ 1][c] = n0;
      s1[p ^ 1][c] = n1;
      ast[(size_t)t * AST_STRIDE + c] = n0;
    }
    __syncthreads();
    p ^= 1;
  }

  float f0 = NEGF, f1 = NEGF;
  if (c < CMAX && c <= BUDGET) { f0 = s0[p][c] + TRANS_T; f1 = s1[p][c]; }
  float lm = fmaxf(f0, f1);
#pragma unroll
  for (int off = 32; off > 0; off >>= 1) lm = fmaxf(lm, __shfl_down(lm, off, 64));
  if (lane == 0) smax[wid] = lm;
  __syncthreads();
  float gm = fmaxf(fmaxf(smax[0], smax[1]), smax[2]);
  float es = __expf(f0 - gm) + __expf(f1 - gm);
#pragma unroll
  for (int off = 32; off > 0; off >>= 1) es += __shfl_down(es, off, 64);
  if (lane == 0) ssum[wid] = es;
  __syncthreads();
  float lz = gm + logf(ssum[0] + ssum[1] + ssum[2]);
  __syncthreads();

  float bb0 = NEGF, bb1 = NEGF;
  if (c < CMAX) {
    bb0 = (c <= BUDGET) ? TRANS_T : NEGF;
    bb1 = (c <= BUDGET) ? 0.0f : NEGF;
  }
  s0[0][c] = bb0; s1[0][c] = bb1;
  s0[1][c] = NEGF; s1[1][c] = NEGF;
  float term = (c < CMAX) ? __expf(ast[(size_t)(TT_LEN - 1) * AST_STRIDE + c] + bb0 - lz) : 0.0f;
#pragma unroll
  for (int off = 32; off > 0; off >>= 1) term += __shfl_down(term, off, 64);
  if (lane == 0) part[0][wid] = term;
  __syncthreads();
  if (c == 0) out[b * TT_LEN + (TT_LEN - 1)] = part[0][0] + part[0][1] + part[0][2];

  int q = 0;
#pragma unroll 1
  for (int t = TT_LEN - 1; t >= 1; --t) {
    float u0t = u0[t];
    float tm = 0.0f;
    if (c < CMAX) {
      float bp = s0[q][c + 1];
      float b1c = s1[q][c];
      float nb0 = la(u0t + TRANS_T + bp, b1c);
      float nb1 = la(u0t + bp, b1c);
      tm = __expf(ast[(size_t)(t - 1) * AST_STRIDE + c] + nb0 - lz);
      s0[q ^ 1][c] = nb0;
      s1[q ^ 1][c] = nb1;
    }
#pragma unroll
    for (int off = 32; off > 0; off >>= 1) tm += __shfl_down(tm, off, 64);
    if (lane == 0) part[t & 1][wid] = tm;
    __syncthreads();
    if (c == 0) out[b * TT_LEN + (t - 1)] = part[t & 1][0] + part[t & 1][1] + part[t & 1][2];
    q ^= 1;
  }
}

// ---------------------------------------------------------------------------
extern "C" void kernel_launch(void* const* d_in, const int* in_sizes, int n_in,
                              void* d_out, int out_size, void* d_ws, size_t ws_size,
                              hipStream_t stream) {
  const int* x = (const int*)d_in[0];
  const float* embed = (const float*)d_in[3];
  const float* wi_f = (const float*)d_in[4];
  const float* wh_f = (const float*)d_in[5];
  const float* bf = (const float*)d_in[6];
  const float* wi_b = (const float*)d_in[7];
  const float* wh_b = (const float*)d_in[8];
  const float* bbias = (const float*)d_in[9];
  const float* w_out = (const float*)d_in[10];
  const float* b_out = (const float*)d_in[11];

  float* ws = (float*)d_ws;
  float* wi_p = ws;                                    // 2*300*1024
  float* b_p = wi_p + 2 * EE * G4;                     // 2*1024
  _Float16* wh_hp = (_Float16*)(b_p + 2 * G4);         // 2*4*32*256*8 halves
  float* emb_dense = b_p + 2 * G4 + (2 * HH * G4) / 2; // 16384*300
  float* xg = emb_dense + (size_t)BB * TT_LEN * EE;    // 2*16384*1024
  float* scores_p4 = xg + (size_t)2 * BB * TT_LEN * G4;  // 256*512
  float* u0 = scores_p4 + 256 * TT_LEN;                // 16384
  float* alpha_store = u0 + BB * TT_LEN;               // 32*512*160
  int* flags = (int*)(alpha_store + (size_t)BB * TT_LEN * AST_STRIDE);  // 256
  unsigned int* hxchg = (unsigned int*)(flags + 256);  // 2*256*32 (parity dbuf)
  float* outp = (float*)d_out;

  prep_weights<<<256, 256, 0, stream>>>(wi_f, wi_b, wh_f, wh_b, bf, bbias,
                                        wi_p, b_p, wh_hp, flags);
  gather_emb<<<BB * TT_LEN, 256, 0, stream>>>(x, embed, emb_dense);
  dim3 g1(G4 / BN, (BB * TT_LEN) / BM, 2);
  xg_gemm<<<g1, 256, 0, stream>>>(emb_dense, wi_p, b_p, xg);
  lstm_rec4<<<256, 256, 0, stream>>>(xg, wh_hp, w_out, scores_p4, hxchg, flags);
  combine_scores<<<(BB * TT_LEN + 255) / 256, 256, 0, stream>>>(scores_p4, b_out, u0);
  dp_kernel<<<BB, 192, 0, stream>>>(u0, alpha_store, outp);
}

// Round 4
// 2457.394 us; speedup vs baseline: 3.0650x; 3.0650x over previous
//
#include <hip/hip_runtime.h>
#include <math.h>

// Problem constants (reference: B,T,V,E,H = 32,512,32000,300,256)
#define BB 32
#define TT_LEN 512
#define EE 300
#define HH 256
#define G4 1024          // 4*H
#define CMAX 155         // int(round(0.3*512))+1
#define BUDGET 154       // round(0.3*512)
#define TRANS_T 10.0f    // TRANSITION/TEMP
#define NEGF -1.0e9f
#define INV_TEMP 100.0f  // 1/TEMP
#define AST_STRIDE 160   // padded CMAX

// lstm weight split: k < 2*KL_DW*... : LDS part = 9 uint4-chunks (k<72),
// stream part = 23 uint4-chunks (k=72..255). Each uint4 = 8 f16 k-values
// for one gate column.
#define NCH_L 9
#define NCH_S 23

typedef _Float16 half2v __attribute__((ext_vector_type(2)));

__device__ __forceinline__ float la(float x, float y) {
  float m = fmaxf(x, y);
  float d = fminf(x, y) - m;
  return m + log1pf(__expf(d));
}

__device__ __forceinline__ float sigm(float x) {
  return 1.0f / (1.0f + __expf(-x));
}

__device__ __forceinline__ float dot2acc(unsigned int wd, unsigned int hd, float acc) {
#if __has_builtin(__builtin_amdgcn_fdot2)
  return __builtin_amdgcn_fdot2(__builtin_bit_cast(half2v, wd),
                                __builtin_bit_cast(half2v, hd), acc, false);
#else
  half2v a = __builtin_bit_cast(half2v, wd);
  half2v b = __builtin_bit_cast(half2v, hd);
  return acc + (float)a.x * (float)b.x + (float)a.y * (float)b.y;
#endif
}

__device__ __forceinline__ unsigned int packh(float a, float b) {
  half2v hp;
  hp.x = (_Float16)a;
  hp.y = (_Float16)b;
  return __builtin_bit_cast(unsigned int, hp);
}

// ---------------- K0: weight prep ------------------------------------------
// wi_p: fp32, [dir][k][j'] with j' = u*4+g (gate interleave).
// wh packed f16 dwords (each dword = k-pair (2k,2k+1) of one gate column j):
//   LDS part  wlds_h: dword idx ((dir*NCH_L + c)*1024 + j)*4 + d, k0 = 8c+2d
//   stream    wstr_h: dword idx ((dir*NCH_S + g)*1024 + j)*4 + d, k0 = 72+8g+2d
__global__ void prep_weights(const float* wi_f, const float* wi_b,
                             const float* wh_f, const float* wh_b,
                             const float* b_f, const float* b_b,
                             float* wi_p, float* b_p,
                             unsigned int* wlds_h, unsigned int* wstr_h) {
  int idx = blockIdx.x * blockDim.x + threadIdx.x;
  int stride = gridDim.x * blockDim.x;
  for (int i = idx; i < 2 * EE * G4; i += stride) {
    int dir = i / (EE * G4);
    int r = (i / G4) % EE;
    int j = i % G4;
    int g = j & 3, u = j >> 2;
    const float* src = dir ? wi_b : wi_f;
    wi_p[i] = src[r * G4 + g * HH + u];
  }
  // LDS-part dwords: 2 * NCH_L * 1024 * 4
  for (int i = idx; i < 2 * NCH_L * 4096; i += stride) {
    int dir = i / (NCH_L * 4096);
    int r = i % (NCH_L * 4096);
    int c = r / 4096;
    int r2 = r % 4096;
    int j = r2 >> 2, d = r2 & 3;
    int g = j & 3, u = j >> 2;
    int k0 = 8 * c + 2 * d;
    const float* src = dir ? wh_b : wh_f;
    wlds_h[i] = packh(src[k0 * G4 + g * HH + u], src[(k0 + 1) * G4 + g * HH + u]);
  }
  // stream-part dwords: 2 * NCH_S * 1024 * 4
  for (int i = idx; i < 2 * NCH_S * 4096; i += stride) {
    int dir = i / (NCH_S * 4096);
    int r = i % (NCH_S * 4096);
    int gch = r / 4096;
    int r2 = r % 4096;
    int j = r2 >> 2, d = r2 & 3;
    int g = j & 3, u = j >> 2;
    int k0 = 8 * NCH_L + 8 * gch + 2 * d;
    const float* src = dir ? wh_b : wh_f;
    wstr_h[i] = packh(src[k0 * G4 + g * HH + u], src[(k0 + 1) * G4 + g * HH + u]);
  }
  for (int i = idx; i < 2 * G4; i += stride) {
    int dir = i / G4;
    int j = i % G4;
    int g = j & 3, u = j >> 2;
    const float* src = dir ? b_b : b_f;
    b_p[i] = src[g * HH + u];
  }
}

// ---------------- K_emb: gather embedding rows into dense (B*T, E) ---------
__global__ void gather_emb(const int* x, const float* embed, float* emb_dense) {
  int row = blockIdx.x;
  int v = x[row];
  const float* src = embed + (size_t)v * EE;
  float* dst = emb_dense + (size_t)row * EE;
  for (int k = threadIdx.x; k < EE; k += blockDim.x) dst[k] = src[k];
}

// ---------------- K1: xg = emb @ Wi_perm + b_perm  (fp32 tiled GEMM) -------
#define BM 64
#define BN 64
#define BK 60
__global__ __launch_bounds__(256) void xg_gemm(const float* __restrict__ emb,
                                               const float* __restrict__ wi_p,
                                               const float* __restrict__ b_p,
                                               float* __restrict__ xg) {
  __shared__ float As[BK][68];
  __shared__ float Bs[BK][BN];
  int dir = blockIdx.z;
  int row0 = blockIdx.y * BM;
  int col0 = blockIdx.x * BN;
  const float* Wsrc = wi_p + (size_t)dir * EE * G4;
  int tid = threadIdx.x;
  int ty = tid >> 4, tx = tid & 15;
  float acc[4][4] = {};
  for (int k0 = 0; k0 < EE; k0 += BK) {
    for (int e = tid; e < BM * BK; e += 256) {
      int m = e / BK, k = e % BK;
      As[k][m] = emb[(size_t)(row0 + m) * EE + k0 + k];
    }
    for (int e = tid; e < BK * BN; e += 256) {
      int k = e >> 6, n = e & 63;
      Bs[k][n] = Wsrc[(size_t)(k0 + k) * G4 + col0 + n];
    }
    __syncthreads();
#pragma unroll 4
    for (int k = 0; k < BK; ++k) {
      float4 a = *(const float4*)&As[k][ty << 2];
      float4 b4 = *(const float4*)&Bs[k][tx << 2];
      acc[0][0] += a.x * b4.x; acc[0][1] += a.x * b4.y; acc[0][2] += a.x * b4.z; acc[0][3] += a.x * b4.w;
      acc[1][0] += a.y * b4.x; acc[1][1] += a.y * b4.y; acc[1][2] += a.y * b4.z; acc[1][3] += a.y * b4.w;
      acc[2][0] += a.z * b4.x; acc[2][1] += a.z * b4.y; acc[2][2] += a.z * b4.z; acc[2][3] += a.z * b4.w;
      acc[3][0] += a.w * b4.x; acc[3][1] += a.w * b4.y; acc[3][2] += a.w * b4.z; acc[3][3] += a.w * b4.w;
    }
    __syncthreads();
  }
  float4 bias = *(const float4*)&b_p[dir * G4 + col0 + (tx << 2)];
#pragma unroll
  for (int i = 0; i < 4; ++i) {
    float4 o;
    o.x = acc[i][0] + bias.x;
    o.y = acc[i][1] + bias.y;
    o.z = acc[i][2] + bias.z;
    o.w = acc[i][3] + bias.w;
    *(float4*)&xg[(size_t)(dir * (BB * TT_LEN) + row0 + (ty << 2) + i) * G4 + col0 + (tx << 2)] = o;
  }
}

// ---------------- K2: LSTM recurrence, 1 block per (dir,b), NO cross-CU sync
// 1024 threads (16 waves), thread j owns permuted gate column j.
// Weights f16: k<72 resident in LDS (144 KB, copied once); k=72..255
// streamed from L2 each step (368 KB/step) through a depth-8 ring of
// uint4 loads. h (256 f16, packed pairs) lives in LDS, broadcast-read.
__global__ __launch_bounds__(1024, 1) void lstm_hyb(
    const float* __restrict__ xg, const unsigned int* __restrict__ wlds_h,
    const uint4* __restrict__ wstr, const float* __restrict__ w_out,
    float* __restrict__ scores_part) {
  int bid = blockIdx.x;            // 64 blocks: dir*32 + b
  int dir = bid >> 5, b = bid & 31;
  int j = threadIdx.x;             // gate column 0..1023
  int lane = j & 63, wid = j >> 6;

  __shared__ uint4 wlds[NCH_L * 1024];   // 144 KB
  __shared__ uint4 hpk4[32];             // 256 h as 128 packed-f16 dwords
  __shared__ float gates[1024];
  __shared__ float wpart[2][4];

  // stage LDS weight slice (contiguous 144 KB per dir)
  const uint4* wsrcl = (const uint4*)wlds_h + (size_t)dir * (NCH_L * 1024);
  for (int i = j; i < NCH_L * 1024; i += 1024) wlds[i] = wsrcl[i];
  if (j < 32) hpk4[j] = uint4{0, 0, 0, 0};
  __syncthreads();

  const float* xgbase =
      xg + (size_t)(dir * (BB * TT_LEN) + b * TT_LEN) * G4 + j;
  const uint4* wsb = wstr + (size_t)dir * (NCH_S * 1024) + j;
  float wo = (j < HH) ? w_out[dir * HH + j] : 0.0f;
  float cstate = 0.0f;

  int t0 = dir ? (TT_LEN - 1) : 0;
  float xg_next = xgbase[(size_t)t0 * G4];
  const unsigned int* hpkd = (const unsigned int*)hpk4;

#pragma unroll 1
  for (int s = 0; s < TT_LEN; ++s) {
    int t = dir ? (TT_LEN - 1 - s) : s;
    float acc = xg_next;
    if (s + 1 < TT_LEN) {
      int t2 = dir ? (TT_LEN - 2 - s) : (s + 1);
      xg_next = xgbase[(size_t)t2 * G4];
    }
    // prologue: 8 stream chunks in flight
    uint4 wbuf[8];
#pragma unroll
    for (int i = 0; i < 8; ++i) wbuf[i] = wsb[i * 1024];
    // LDS-resident part: k < 72
#pragma unroll
    for (int c = 0; c < NCH_L; ++c) {
      uint4 w = wlds[c * 1024 + j];
      uint4 h = hpk4[c];
      acc = dot2acc(w.x, h.x, acc);
      acc = dot2acc(w.y, h.y, acc);
      acc = dot2acc(w.z, h.z, acc);
      acc = dot2acc(w.w, h.w, acc);
    }
    // streamed part: k = 72..255, ring depth 8
#pragma unroll
    for (int g = 0; g < NCH_S; ++g) {
      uint4 w = wbuf[g & 7];
      if (g + 8 < NCH_S) wbuf[g & 7] = wsb[(g + 8) * 1024];
      uint4 h = hpk4[NCH_L + g];
      acc = dot2acc(w.x, h.x, acc);
      acc = dot2acc(w.y, h.y, acc);
      acc = dot2acc(w.z, h.z, acc);
      acc = dot2acc(w.w, h.w, acc);
    }
    gates[j] = acc;
    __syncthreads();

    if (j < HH) {
      float4 g4 = ((const float4*)gates)[j];
      float ig = sigm(g4.x);
      float fg = sigm(g4.y);
      float gg = tanhf(g4.z);
      float og = sigm(g4.w);
      cstate = fg * cstate + ig * gg;
      float h = og * tanhf(cstate);
      float prod = h * wo;
#pragma unroll
      for (int off = 32; off > 0; off >>= 1) prod += __shfl_down(prod, off, 64);
      if (lane == 0) wpart[s & 1][wid] = prod;
      float hn = __shfl_down(h, 1, 64);
      if (!(j & 1)) ((unsigned int*)hpk4)[j >> 1] = packh(h, hn);
    }
    __syncthreads();
    if (j == 0) {
      scores_part[(size_t)(dir * BB + b) * TT_LEN + t] =
          wpart[s & 1][0] + wpart[s & 1][1] + wpart[s & 1][2] + wpart[s & 1][3];
    }
    (void)hpkd;
  }
}

// ---------------- K3: u0 = (score_f + score_b + b_out) / TEMP --------------
__global__ void combine_scores(const float* __restrict__ scores_part,
                               const float* __restrict__ b_out,
                               float* __restrict__ u0) {
  int i = blockIdx.x * blockDim.x + threadIdx.x;
  if (i < BB * TT_LEN)
    u0[i] = (scores_part[i] + scores_part[BB * TT_LEN + i] + b_out[0]) * INV_TEMP;
}

// ---------------- K4: CRF forward-backward marginals -----------------------
__global__ __launch_bounds__(192) void dp_kernel(const float* __restrict__ u0all,
                                                 float* __restrict__ alpha_store,
                                                 float* __restrict__ out) {
  int b = blockIdx.x;
  int c = threadIdx.x;
  int lane = c & 63, wid = c >> 6;
  const float* u0 = u0all + b * TT_LEN;
  float* ast = alpha_store + (size_t)b * TT_LEN * AST_STRIDE;
  __shared__ float s0[2][AST_STRIDE], s1[2][AST_STRIDE];
  __shared__ float part[2][4];
  __shared__ float smax[4], ssum[4];

  s0[0][c] = NEGF; s0[1][c] = NEGF; s1[0][c] = NEGF; s1[1][c] = NEGF;
  if (c == 1) s0[0][1] = u0[0] + TRANS_T;
  if (c == 0) s1[0][0] = 0.0f;
  if (c < CMAX) ast[c] = s0[0][c];
  __syncthreads();
  int p = 0;
#pragma unroll 1
  for (int t = 1; t < TT_LEN; ++t) {
    float u0t = u0[t];
    if (c < CMAX) {
      float am0 = (c >= 1) ? s0[p][c - 1] : NEGF;
      float am1 = (c >= 1) ? s1[p][c - 1] : NEGF;
      float n0 = u0t + la(am0 + TRANS_T, am1);
      float n1 = la(s0[p][c], s1[p][c]);
      s0[p ^ 1][c] = n0;
      s1[p ^ 1][c] = n1;
      ast[(size_t)t * AST_STRIDE + c] = n0;
    }
    __syncthreads();
    p ^= 1;
  }

  float f0 = NEGF, f1 = NEGF;
  if (c < CMAX && c <= BUDGET) { f0 = s0[p][c] + TRANS_T; f1 = s1[p][c]; }
  float lm = fmaxf(f0, f1);
#pragma unroll
  for (int off = 32; off > 0; off >>= 1) lm = fmaxf(lm, __shfl_down(lm, off, 64));
  if (lane == 0) smax[wid] = lm;
  __syncthreads();
  float gm = fmaxf(fmaxf(smax[0], smax[1]), smax[2]);
  float es = __expf(f0 - gm) + __expf(f1 - gm);
#pragma unroll
  for (int off = 32; off > 0; off >>= 1) es += __shfl_down(es, off, 64);
  if (lane == 0) ssum[wid] = es;
  __syncthreads();
  float lz = gm + logf(ssum[0] + ssum[1] + ssum[2]);
  __syncthreads();

  float bb0 = NEGF, bb1 = NEGF;
  if (c < CMAX) {
    bb0 = (c <= BUDGET) ? TRANS_T : NEGF;
    bb1 = (c <= BUDGET) ? 0.0f : NEGF;
  }
  s0[0][c] = bb0; s1[0][c] = bb1;
  s0[1][c] = NEGF; s1[1][c] = NEGF;
  float term = (c < CMAX) ? __expf(ast[(size_t)(TT_LEN - 1) * AST_STRIDE + c] + bb0 - lz) : 0.0f;
#pragma unroll
  for (int off = 32; off > 0; off >>= 1) term += __shfl_down(term, off, 64);
  if (lane == 0) part[0][wid] = term;
  __syncthreads();
  if (c == 0) out[b * TT_LEN + (TT_LEN - 1)] = part[0][0] + part[0][1] + part[0][2];

  int q = 0;
#pragma unroll 1
  for (int t = TT_LEN - 1; t >= 1; --t) {
    float u0t = u0[t];
    float tm = 0.0f;
    if (c < CMAX) {
      float bp = s0[q][c + 1];
      float b1c = s1[q][c];
      float nb0 = la(u0t + TRANS_T + bp, b1c);
      float nb1 = la(u0t + bp, b1c);
      tm = __expf(ast[(size_t)(t - 1) * AST_STRIDE + c] + nb0 - lz);
      s0[q ^ 1][c] = nb0;
      s1[q ^ 1][c] = nb1;
    }
#pragma unroll
    for (int off = 32; off > 0; off >>= 1) tm += __shfl_down(tm, off, 64);
    if (lane == 0) part[t & 1][wid] = tm;
    __syncthreads();
    if (c == 0) out[b * TT_LEN + (t - 1)] = part[t & 1][0] + part[t & 1][1] + part[t & 1][2];
    q ^= 1;
  }
}

// ---------------------------------------------------------------------------
extern "C" void kernel_launch(void* const* d_in, const int* in_sizes, int n_in,
                              void* d_out, int out_size, void* d_ws, size_t ws_size,
                              hipStream_t stream) {
  const int* x = (const int*)d_in[0];
  const float* embed = (const float*)d_in[3];
  const float* wi_f = (const float*)d_in[4];
  const float* wh_f = (const float*)d_in[5];
  const float* bf = (const float*)d_in[6];
  const float* wi_b = (const float*)d_in[7];
  const float* wh_b = (const float*)d_in[8];
  const float* bbias = (const float*)d_in[9];
  const float* w_out = (const float*)d_in[10];
  const float* b_out = (const float*)d_in[11];

  float* ws = (float*)d_ws;
  float* wi_p = ws;                                     // 2*300*1024
  float* b_p = wi_p + 2 * EE * G4;                      // 2*1024
  unsigned int* wlds_h = (unsigned int*)(b_p + 2 * G4); // 2*9*4096 dwords
  unsigned int* wstr_h = wlds_h + 2 * NCH_L * 4096;     // 2*23*4096 dwords
  float* emb_dense = (float*)(wstr_h + 2 * NCH_S * 4096);  // 16384*300
  float* xg = emb_dense + (size_t)BB * TT_LEN * EE;     // 2*16384*1024
  float* scores_part = xg + (size_t)2 * BB * TT_LEN * G4;  // 2*16384
  float* u0 = scores_part + 2 * BB * TT_LEN;            // 16384
  float* alpha_store = u0 + BB * TT_LEN;                // 32*512*160
  float* outp = (float*)d_out;

  prep_weights<<<256, 256, 0, stream>>>(wi_f, wi_b, wh_f, wh_b, bf, bbias,
                                        wi_p, b_p, wlds_h, wstr_h);
  gather_emb<<<BB * TT_LEN, 256, 0, stream>>>(x, embed, emb_dense);
  dim3 g1(G4 / BN, (BB * TT_LEN) / BM, 2);
  xg_gemm<<<g1, 256, 0, stream>>>(emb_dense, wi_p, b_p, xg);
  lstm_hyb<<<64, 1024, 0, stream>>>(xg, wlds_h, (const uint4*)wstr_h, w_out,
                                    scores_part);
  combine_scores<<<(BB * TT_LEN + 255) / 256, 256, 0, stream>>>(scores_part, b_out, u0);
  dp_kernel<<<BB, 192, 0, stream>>>(u0, alpha_store, outp);
}

// Round 5
// 2263.330 us; speedup vs baseline: 3.3278x; 1.0857x over previous
//
#include <hip/hip_runtime.h>
#include <math.h>

// Problem constants (reference: B,T,V,E,H = 32,512,32000,300,256)
#define BB 32
#define TT_LEN 512
#define EE 300
#define KPAD 320         // EE padded to multiple of 32 for MFMA K
#define HH 256
#define G4 1024          // 4*H
#define CMAX 155         // int(round(0.3*512))+1
#define BUDGET 154       // round(0.3*512)
#define TRANS_T 10.0f    // TRANSITION/TEMP
#define NEGF -1.0e9f
#define INV_TEMP 100.0f  // 1/TEMP
#define AST_STRIDE 160   // padded CMAX

// lstm weight split: LDS part = 9 uint4-chunks (k<72), stream part = 23
// uint4-chunks (k=72..255). Each uint4 = 8 f16 k-values for one gate column.
#define NCH_L 9
#define NCH_S 23

typedef _Float16 half2v __attribute__((ext_vector_type(2)));
typedef _Float16 half8 __attribute__((ext_vector_type(8)));
typedef float f32x4 __attribute__((ext_vector_type(4)));

__device__ __forceinline__ float la(float x, float y) {
  float m = fmaxf(x, y);
  float d = fminf(x, y) - m;
  return m + log1pf(__expf(d));
}

__device__ __forceinline__ float sigm(float x) {
  return 1.0f / (1.0f + __expf(-x));
}

__device__ __forceinline__ float dot2acc(unsigned int wd, unsigned int hd, float acc) {
#if __has_builtin(__builtin_amdgcn_fdot2)
  return __builtin_amdgcn_fdot2(__builtin_bit_cast(half2v, wd),
                                __builtin_bit_cast(half2v, hd), acc, false);
#else
  half2v a = __builtin_bit_cast(half2v, wd);
  half2v b = __builtin_bit_cast(half2v, hd);
  return acc + (float)a.x * (float)b.x + (float)a.y * (float)b.y;
#endif
}

__device__ __forceinline__ unsigned int packh(float a, float b) {
  half2v hp;
  hp.x = (_Float16)a;
  hp.y = (_Float16)b;
  return __builtin_bit_cast(unsigned int, hp);
}

// ---------------- K0: weight prep ------------------------------------------
// wi_t: f16 [dir][j'][k] with j' = u*4+g, k padded to KPAD (zeros k>=300) —
//   column-major so MFMA B-fragments (8 contiguous k per lane) load directly.
// wh packed f16 dwords (each dword = k-pair (2k,2k+1) of one gate column j):
//   LDS part  wlds_h: dword idx ((dir*NCH_L + c)*1024 + j)*4 + d, k0 = 8c+2d
//   stream    wstr_h: dword idx ((dir*NCH_S + g)*1024 + j)*4 + d, k0 = 72+8g+2d
__global__ void prep_weights(const float* wi_f, const float* wi_b,
                             const float* wh_f, const float* wh_b,
                             const float* b_f, const float* b_b,
                             _Float16* wi_t, float* b_p,
                             unsigned int* wlds_h, unsigned int* wstr_h) {
  int idx = blockIdx.x * blockDim.x + threadIdx.x;
  int stride = gridDim.x * blockDim.x;
  // wi transpose: 2 * 1024 * KPAD f16
  for (int i = idx; i < 2 * G4 * KPAD; i += stride) {
    int dir = i / (G4 * KPAD);
    int r = i % (G4 * KPAD);
    int j = r / KPAD;
    int k = r % KPAD;
    int g = j & 3, u = j >> 2;
    const float* src = dir ? wi_b : wi_f;
    wi_t[i] = (k < EE) ? (_Float16)src[(size_t)k * G4 + g * HH + u] : (_Float16)0.0f;
  }
  // LDS-part dwords: 2 * NCH_L * 1024 * 4
  for (int i = idx; i < 2 * NCH_L * 4096; i += stride) {
    int dir = i / (NCH_L * 4096);
    int r = i % (NCH_L * 4096);
    int c = r / 4096;
    int r2 = r % 4096;
    int j = r2 >> 2, d = r2 & 3;
    int g = j & 3, u = j >> 2;
    int k0 = 8 * c + 2 * d;
    const float* src = dir ? wh_b : wh_f;
    wlds_h[i] = packh(src[k0 * G4 + g * HH + u], src[(k0 + 1) * G4 + g * HH + u]);
  }
  // stream-part dwords: 2 * NCH_S * 1024 * 4
  for (int i = idx; i < 2 * NCH_S * 4096; i += stride) {
    int dir = i / (NCH_S * 4096);
    int r = i % (NCH_S * 4096);
    int gch = r / 4096;
    int r2 = r % 4096;
    int j = r2 >> 2, d = r2 & 3;
    int g = j & 3, u = j >> 2;
    int k0 = 8 * NCH_L + 8 * gch + 2 * d;
    const float* src = dir ? wh_b : wh_f;
    wstr_h[i] = packh(src[k0 * G4 + g * HH + u], src[(k0 + 1) * G4 + g * HH + u]);
  }
  for (int i = idx; i < 2 * G4; i += stride) {
    int dir = i / G4;
    int j = i % G4;
    int g = j & 3, u = j >> 2;
    const float* src = dir ? b_b : b_f;
    b_p[i] = src[g * HH + u];
  }
}

// ---------------- K_emb: gather embedding rows -> f16 dense (B*T, KPAD) ----
__global__ void gather_emb(const int* x, const float* embed, _Float16* emb_h) {
  int row = blockIdx.x;
  int v = x[row];
  const float* src = embed + (size_t)v * EE;
  _Float16* dst = emb_h + (size_t)row * KPAD;
  for (int k = threadIdx.x; k < KPAD; k += blockDim.x)
    dst[k] = (k < EE) ? (_Float16)src[k] : (_Float16)0.0f;
}

// ---------------- K1: xg = emb_h @ wi_t^T + b_p  (f16 MFMA) ----------------
// Block = 256 threads (4 waves), computes 64(m) x 64(n) of xg for one dir.
// Wave w owns m-subtile [m0+16w, +16). Fragments loaded DIRECTLY from global
// (no LDS): A[m=lane&15][k=quad*8+j] = emb_h[m][k...]; B[n=lane&15][k same]
// = wi_t[dir][n][k...]. Block working set ~8 KB -> L1; B (640 KB/dir) L2-hot.
// D layout: col(n)=lane&15, row(m)=quad*4+reg (m89-verified convention).
__global__ __launch_bounds__(256) void xg_mfma(
    const _Float16* __restrict__ emb_h, const _Float16* __restrict__ wi_t,
    const float* __restrict__ b_p, float* __restrict__ xg) {
  int dir = blockIdx.z;
  int n0 = blockIdx.x * 64;
  int m0 = blockIdx.y * 64;
  int wave = threadIdx.x >> 6;
  int lane = threadIdx.x & 63;
  int l15 = lane & 15, quad = lane >> 4;

  const _Float16* arow = emb_h + (size_t)(m0 + wave * 16 + l15) * KPAD + quad * 8;
  const _Float16* bbase =
      wi_t + ((size_t)dir * G4 + n0 + l15) * KPAD + quad * 8;

  f32x4 acc[4];
#pragma unroll
  for (int nt = 0; nt < 4; ++nt) acc[nt] = (f32x4){0.f, 0.f, 0.f, 0.f};

#pragma unroll
  for (int kk = 0; kk < KPAD / 32; ++kk) {
    half8 a = *(const half8*)(arow + kk * 32);
#pragma unroll
    for (int nt = 0; nt < 4; ++nt) {
      half8 b = *(const half8*)(bbase + (size_t)nt * 16 * KPAD + kk * 32);
      acc[nt] = __builtin_amdgcn_mfma_f32_16x16x32_f16(a, b, acc[nt], 0, 0, 0);
    }
  }
#pragma unroll
  for (int nt = 0; nt < 4; ++nt) {
    int n = n0 + nt * 16 + l15;
    float bias = b_p[dir * G4 + n];
#pragma unroll
    for (int r = 0; r < 4; ++r) {
      int m = m0 + wave * 16 + quad * 4 + r;
      xg[((size_t)dir * (BB * TT_LEN) + m) * G4 + n] = acc[nt][r] + bias;
    }
  }
}

// ---------------- K2: LSTM recurrence, 1 block per (dir,b), NO cross-CU sync
// 1024 threads (16 waves), thread j owns permuted gate column j.
// Weights f16: k<72 resident in LDS (144 KB, copied once); k=72..255
// streamed from L2 each step (368 KB/step) through a depth-8 ring of
// uint4 loads. Per-CU-L2-BW-bound at ~68 B/cy (round 4 measured).
__global__ __launch_bounds__(1024, 1) void lstm_hyb(
    const float* __restrict__ xg, const unsigned int* __restrict__ wlds_h,
    const uint4* __restrict__ wstr, const float* __restrict__ w_out,
    float* __restrict__ scores_part) {
  int bid = blockIdx.x;            // 64 blocks: dir*32 + b
  int dir = bid >> 5, b = bid & 31;
  int j = threadIdx.x;             // gate column 0..1023
  int lane = j & 63, wid = j >> 6;

  __shared__ uint4 wlds[NCH_L * 1024];   // 144 KB
  __shared__ uint4 hpk4[32];             // 256 h as 128 packed-f16 dwords
  __shared__ float gates[1024];
  __shared__ float wpart[2][4];

  const uint4* wsrcl = (const uint4*)wlds_h + (size_t)dir * (NCH_L * 1024);
  for (int i = j; i < NCH_L * 1024; i += 1024) wlds[i] = wsrcl[i];
  if (j < 32) hpk4[j] = uint4{0, 0, 0, 0};
  __syncthreads();

  const float* xgbase =
      xg + (size_t)(dir * (BB * TT_LEN) + b * TT_LEN) * G4 + j;
  const uint4* wsb = wstr + (size_t)dir * (NCH_S * 1024) + j;
  float wo = (j < HH) ? w_out[dir * HH + j] : 0.0f;
  float cstate = 0.0f;

  int t0 = dir ? (TT_LEN - 1) : 0;
  float xg_next = xgbase[(size_t)t0 * G4];

#pragma unroll 1
  for (int s = 0; s < TT_LEN; ++s) {
    int t = dir ? (TT_LEN - 1 - s) : s;
    float acc = xg_next;
    if (s + 1 < TT_LEN) {
      int t2 = dir ? (TT_LEN - 2 - s) : (s + 1);
      xg_next = xgbase[(size_t)t2 * G4];
    }
    uint4 wbuf[8];
#pragma unroll
    for (int i = 0; i < 8; ++i) wbuf[i] = wsb[i * 1024];
#pragma unroll
    for (int c = 0; c < NCH_L; ++c) {
      uint4 w = wlds[c * 1024 + j];
      uint4 h = hpk4[c];
      acc = dot2acc(w.x, h.x, acc);
      acc = dot2acc(w.y, h.y, acc);
      acc = dot2acc(w.z, h.z, acc);
      acc = dot2acc(w.w, h.w, acc);
    }
#pragma unroll
    for (int g = 0; g < NCH_S; ++g) {
      uint4 w = wbuf[g & 7];
      if (g + 8 < NCH_S) wbuf[g & 7] = wsb[(g + 8) * 1024];
      uint4 h = hpk4[NCH_L + g];
      acc = dot2acc(w.x, h.x, acc);
      acc = dot2acc(w.y, h.y, acc);
      acc = dot2acc(w.z, h.z, acc);
      acc = dot2acc(w.w, h.w, acc);
    }
    gates[j] = acc;
    __syncthreads();

    if (j < HH) {
      float4 g4 = ((const float4*)gates)[j];
      float ig = sigm(g4.x);
      float fg = sigm(g4.y);
      float gg = tanhf(g4.z);
      float og = sigm(g4.w);
      cstate = fg * cstate + ig * gg;
      float h = og * tanhf(cstate);
      float prod = h * wo;
#pragma unroll
      for (int off = 32; off > 0; off >>= 1) prod += __shfl_down(prod, off, 64);
      if (lane == 0) wpart[s & 1][wid] = prod;
      float hn = __shfl_down(h, 1, 64);
      if (!(j & 1)) ((unsigned int*)hpk4)[j >> 1] = packh(h, hn);
    }
    __syncthreads();
    if (j == 0) {
      scores_part[(size_t)(dir * BB + b) * TT_LEN + t] =
          wpart[s & 1][0] + wpart[s & 1][1] + wpart[s & 1][2] + wpart[s & 1][3];
    }
  }
}

// ---------------- K3: u0 = (score_f + score_b + b_out) / TEMP --------------
__global__ void combine_scores(const float* __restrict__ scores_part,
                               const float* __restrict__ b_out,
                               float* __restrict__ u0) {
  int i = blockIdx.x * blockDim.x + threadIdx.x;
  if (i < BB * TT_LEN)
    u0[i] = (scores_part[i] + scores_part[BB * TT_LEN + i] + b_out[0]) * INV_TEMP;
}

// ---------------- K4: CRF forward-backward marginals -----------------------
__global__ __launch_bounds__(192) void dp_kernel(const float* __restrict__ u0all,
                                                 float* __restrict__ alpha_store,
                                                 float* __restrict__ out) {
  int b = blockIdx.x;
  int c = threadIdx.x;
  int lane = c & 63, wid = c >> 6;
  const float* u0 = u0all + b * TT_LEN;
  float* ast = alpha_store + (size_t)b * TT_LEN * AST_STRIDE;
  __shared__ float s0[2][AST_STRIDE], s1[2][AST_STRIDE];
  __shared__ float part[2][4];
  __shared__ float smax[4], ssum[4];

  s0[0][c] = NEGF; s0[1][c] = NEGF; s1[0][c] = NEGF; s1[1][c] = NEGF;
  if (c == 1) s0[0][1] = u0[0] + TRANS_T;
  if (c == 0) s1[0][0] = 0.0f;
  if (c < CMAX) ast[c] = s0[0][c];
  __syncthreads();
  int p = 0;
#pragma unroll 1
  for (int t = 1; t < TT_LEN; ++t) {
    float u0t = u0[t];
    if (c < CMAX) {
      float am0 = (c >= 1) ? s0[p][c - 1] : NEGF;
      float am1 = (c >= 1) ? s1[p][c - 1] : NEGF;
      float n0 = u0t + la(am0 + TRANS_T, am1);
      float n1 = la(s0[p][c], s1[p][c]);
      s0[p ^ 1][c] = n0;
      s1[p ^ 1][c] = n1;
      ast[(size_t)t * AST_STRIDE + c] = n0;
    }
    __syncthreads();
    p ^= 1;
  }

  float f0 = NEGF, f1 = NEGF;
  if (c < CMAX && c <= BUDGET) { f0 = s0[p][c] + TRANS_T; f1 = s1[p][c]; }
  float lm = fmaxf(f0, f1);
#pragma unroll
  for (int off = 32; off > 0; off >>= 1) lm = fmaxf(lm, __shfl_down(lm, off, 64));
  if (lane == 0) smax[wid] = lm;
  __syncthreads();
  float gm = fmaxf(fmaxf(smax[0], smax[1]), smax[2]);
  float es = __expf(f0 - gm) + __expf(f1 - gm);
#pragma unroll
  for (int off = 32; off > 0; off >>= 1) es += __shfl_down(es, off, 64);
  if (lane == 0) ssum[wid] = es;
  __syncthreads();
  float lz = gm + logf(ssum[0] + ssum[1] + ssum[2]);
  __syncthreads();

  float bb0 = NEGF, bb1 = NEGF;
  if (c < CMAX) {
    bb0 = (c <= BUDGET) ? TRANS_T : NEGF;
    bb1 = (c <= BUDGET) ? 0.0f : NEGF;
  }
  s0[0][c] = bb0; s1[0][c] = bb1;
  s0[1][c] = NEGF; s1[1][c] = NEGF;
  float term = (c < CMAX) ? __expf(ast[(size_t)(TT_LEN - 1) * AST_STRIDE + c] + bb0 - lz) : 0.0f;
#pragma unroll
  for (int off = 32; off > 0; off >>= 1) term += __shfl_down(term, off, 64);
  if (lane == 0) part[0][wid] = term;
  __syncthreads();
  if (c == 0) out[b * TT_LEN + (TT_LEN - 1)] = part[0][0] + part[0][1] + part[0][2];

  int q = 0;
#pragma unroll 1
  for (int t = TT_LEN - 1; t >= 1; --t) {
    float u0t = u0[t];
    float tm = 0.0f;
    if (c < CMAX) {
      float bp = s0[q][c + 1];
      float b1c = s1[q][c];
      float nb0 = la(u0t + TRANS_T + bp, b1c);
      float nb1 = la(u0t + bp, b1c);
      tm = __expf(ast[(size_t)(t - 1) * AST_STRIDE + c] + nb0 - lz);
      s0[q ^ 1][c] = nb0;
      s1[q ^ 1][c] = nb1;
    }
#pragma unroll
    for (int off = 32; off > 0; off >>= 1) tm += __shfl_down(tm, off, 64);
    if (lane == 0) part[t & 1][wid] = tm;
    __syncthreads();
    if (c == 0) out[b * TT_LEN + (t - 1)] = part[t & 1][0] + part[t & 1][1] + part[t & 1][2];
    q ^= 1;
  }
}

// ---------------------------------------------------------------------------
extern "C" void kernel_launch(void* const* d_in, const int* in_sizes, int n_in,
                              void* d_out, int out_size, void* d_ws, size_t ws_size,
                              hipStream_t stream) {
  const int* x = (const int*)d_in[0];
  const float* embed = (const float*)d_in[3];
  const float* wi_f = (const float*)d_in[4];
  const float* wh_f = (const float*)d_in[5];
  const float* bf = (const float*)d_in[6];
  const float* wi_b = (const float*)d_in[7];
  const float* wh_b = (const float*)d_in[8];
  const float* bbias = (const float*)d_in[9];
  const float* w_out = (const float*)d_in[10];
  const float* b_out = (const float*)d_in[11];

  float* ws = (float*)d_ws;
  float* b_p = ws;                                      // 2*1024 f32
  unsigned int* wlds_h = (unsigned int*)(b_p + 2 * G4); // 2*9*4096 dwords
  unsigned int* wstr_h = wlds_h + 2 * NCH_L * 4096;     // 2*23*4096 dwords
  _Float16* wi_t = (_Float16*)(wstr_h + 2 * NCH_S * 4096);  // 2*1024*320 f16
  _Float16* emb_h = wi_t + (size_t)2 * G4 * KPAD;       // 16384*320 f16
  float* xg = (float*)(emb_h + (size_t)BB * TT_LEN * KPAD);  // 2*16384*1024 f32
  float* scores_part = xg + (size_t)2 * BB * TT_LEN * G4;    // 2*16384
  float* u0 = scores_part + 2 * BB * TT_LEN;            // 16384
  float* alpha_store = u0 + BB * TT_LEN;                // 32*512*160
  float* outp = (float*)d_out;

  prep_weights<<<256, 256, 0, stream>>>(wi_f, wi_b, wh_f, wh_b, bf, bbias,
                                        wi_t, b_p, wlds_h, wstr_h);
  gather_emb<<<BB * TT_LEN, 256, 0, stream>>>(x, embed, emb_h);
  dim3 g1(G4 / 64, (BB * TT_LEN) / 64, 2);
  xg_mfma<<<g1, 256, 0, stream>>>(emb_h, wi_t, b_p, xg);
  lstm_hyb<<<64, 1024, 0, stream>>>(xg, wlds_h, (const uint4*)wstr_h, w_out,
                                    scores_part);
  combine_scores<<<(BB * TT_LEN + 255) / 256, 256, 0, stream>>>(scores_part, b_out, u0);
  dp_kernel<<<BB, 192, 0, stream>>>(u0, alpha_store, outp);
}

// Round 7
// 1970.017 us; speedup vs baseline: 3.8233x; 1.1489x over previous
//
#include <hip/hip_runtime.h>
#include <math.h>

// Problem constants (reference: B,T,V,E,H = 32,512,32000,300,256)
#define BB 32
#define TT_LEN 512
#define EE 300
#define KPAD 320         // EE padded to multiple of 32 for MFMA K
#define HH 256
#define G4 1024          // 4*H
#define CMAX 155         // int(round(0.3*512))+1
#define TRANS_T 10.0f    // TRANSITION/TEMP
#define NEGF -1.0e9f
#define INV_TEMP 100.0f  // 1/TEMP
#define AST_STRIDE 160   // round-5 footprint; slot-2 accesses predicated l<27

// lstm weight split: LDS part = 9 uint4-chunks (k<72), stream part = 23
// uint4-chunks (k=72..255). Each uint4 = 8 f16 k-values for one gate column.
#define NCH_L 9
#define NCH_S 23

typedef _Float16 half2v __attribute__((ext_vector_type(2)));
typedef _Float16 half8 __attribute__((ext_vector_type(8)));
typedef float f32x4 __attribute__((ext_vector_type(4)));

__device__ __forceinline__ float la(float x, float y) {
  // logaddexp via hw transcendentals; error <=1e-7/step
  float m = fmaxf(x, y);
  float d = fminf(x, y) - m;
  return m + __logf(1.0f + __expf(d));
}

__device__ __forceinline__ float sigm(float x) {
  return 1.0f / (1.0f + __expf(-x));
}

__device__ __forceinline__ float dot2acc(unsigned int wd, unsigned int hd, float acc) {
#if __has_builtin(__builtin_amdgcn_fdot2)
  return __builtin_amdgcn_fdot2(__builtin_bit_cast(half2v, wd),
                                __builtin_bit_cast(half2v, hd), acc, false);
#else
  half2v a = __builtin_bit_cast(half2v, wd);
  half2v b = __builtin_bit_cast(half2v, hd);
  return acc + (float)a.x * (float)b.x + (float)a.y * (float)b.y;
#endif
}

__device__ __forceinline__ unsigned int packh(float a, float b) {
  half2v hp;
  hp.x = (_Float16)a;
  hp.y = (_Float16)b;
  return __builtin_bit_cast(unsigned int, hp);
}

// ---------------- K0: weight prep (round-5 known-good version) -------------
// wi_t: f16 [dir][j'][k], j' = u*4+g, k padded to KPAD (zeros k>=300).
// wh packed f16 dwords (dword = k-pair (2k,2k+1) of gate column j):
//   LDS part  wlds_h: idx ((dir*NCH_L + c)*1024 + j)*4 + d, k0 = 8c+2d
//   stream    wstr_h: idx ((dir*NCH_S + g)*1024 + j)*4 + d, k0 = 72+8g+2d
__global__ void prep_weights(const float* wi_f, const float* wi_b,
                             const float* wh_f, const float* wh_b,
                             const float* b_f, const float* b_b,
                             _Float16* wi_t, float* b_p,
                             unsigned int* wlds_h, unsigned int* wstr_h) {
  int idx = blockIdx.x * blockDim.x + threadIdx.x;
  int stride = gridDim.x * blockDim.x;
  // wi transpose: 2 * 1024 * KPAD f16
  for (int i = idx; i < 2 * G4 * KPAD; i += stride) {
    int dir = i / (G4 * KPAD);
    int r = i % (G4 * KPAD);
    int j = r / KPAD;
    int k = r % KPAD;
    int g = j & 3, u = j >> 2;
    const float* src = dir ? wi_b : wi_f;
    wi_t[i] = (k < EE) ? (_Float16)src[(size_t)k * G4 + g * HH + u] : (_Float16)0.0f;
  }
  // LDS-part dwords: 2 * NCH_L * 1024 * 4
  for (int i = idx; i < 2 * NCH_L * 4096; i += stride) {
    int dir = i / (NCH_L * 4096);
    int r = i % (NCH_L * 4096);
    int c = r / 4096;
    int r2 = r % 4096;
    int j = r2 >> 2, d = r2 & 3;
    int g = j & 3, u = j >> 2;
    int k0 = 8 * c + 2 * d;
    const float* src = dir ? wh_b : wh_f;
    wlds_h[i] = packh(src[k0 * G4 + g * HH + u], src[(k0 + 1) * G4 + g * HH + u]);
  }
  // stream-part dwords: 2 * NCH_S * 1024 * 4
  for (int i = idx; i < 2 * NCH_S * 4096; i += stride) {
    int dir = i / (NCH_S * 4096);
    int r = i % (NCH_S * 4096);
    int gch = r / 4096;
    int r2 = r % 4096;
    int j = r2 >> 2, d = r2 & 3;
    int g = j & 3, u = j >> 2;
    int k0 = 8 * NCH_L + 8 * gch + 2 * d;
    const float* src = dir ? wh_b : wh_f;
    wstr_h[i] = packh(src[k0 * G4 + g * HH + u], src[(k0 + 1) * G4 + g * HH + u]);
  }
  for (int i = idx; i < 2 * G4; i += stride) {
    int dir = i / G4;
    int j = i % G4;
    int g = j & 3, u = j >> 2;
    const float* src = dir ? b_b : b_f;
    b_p[i] = src[g * HH + u];
  }
}

// ---------------- K_emb: gather embedding rows -> f16 dense (B*T, KPAD) ----
__global__ void gather_emb(const int* x, const float* embed, _Float16* emb_h) {
  int row = blockIdx.x;
  int v = x[row];
  const float* src = embed + (size_t)v * EE;
  _Float16* dst = emb_h + (size_t)row * KPAD;
  for (int k = threadIdx.x; k < KPAD; k += blockDim.x)
    dst[k] = (k < EE) ? (_Float16)src[k] : (_Float16)0.0f;
}

// ---------------- K1: xg = emb_h @ wi_t^T + b_p  (f16 MFMA) ----------------
__global__ __launch_bounds__(256) void xg_mfma(
    const _Float16* __restrict__ emb_h, const _Float16* __restrict__ wi_t,
    const float* __restrict__ b_p, float* __restrict__ xg) {
  int dir = blockIdx.z;
  int n0 = blockIdx.x * 64;
  int m0 = blockIdx.y * 64;
  int wave = threadIdx.x >> 6;
  int lane = threadIdx.x & 63;
  int l15 = lane & 15, quad = lane >> 4;

  const _Float16* arow = emb_h + (size_t)(m0 + wave * 16 + l15) * KPAD + quad * 8;
  const _Float16* bbase =
      wi_t + ((size_t)dir * G4 + n0 + l15) * KPAD + quad * 8;

  f32x4 acc[4];
#pragma unroll
  for (int nt = 0; nt < 4; ++nt) acc[nt] = (f32x4){0.f, 0.f, 0.f, 0.f};

#pragma unroll
  for (int kk = 0; kk < KPAD / 32; ++kk) {
    half8 a = *(const half8*)(arow + kk * 32);
#pragma unroll
    for (int nt = 0; nt < 4; ++nt) {
      half8 b = *(const half8*)(bbase + (size_t)nt * 16 * KPAD + kk * 32);
      acc[nt] = __builtin_amdgcn_mfma_f32_16x16x32_f16(a, b, acc[nt], 0, 0, 0);
    }
  }
#pragma unroll
  for (int nt = 0; nt < 4; ++nt) {
    int n = n0 + nt * 16 + l15;
    float bias = b_p[dir * G4 + n];
#pragma unroll
    for (int r = 0; r < 4; ++r) {
      int m = m0 + wave * 16 + quad * 4 + r;
      xg[((size_t)dir * (BB * TT_LEN) + m) * G4 + n] = acc[nt][r] + bias;
    }
  }
}

// ---------------- K2: LSTM recurrence (per-CU L2-BW-bound, unchanged) ------
__global__ __launch_bounds__(1024, 1) void lstm_hyb(
    const float* __restrict__ xg, const unsigned int* __restrict__ wlds_h,
    const uint4* __restrict__ wstr, const float* __restrict__ w_out,
    float* __restrict__ scores_part) {
  int bid = blockIdx.x;            // 64 blocks: dir*32 + b
  int dir = bid >> 5, b = bid & 31;
  int j = threadIdx.x;             // gate column 0..1023
  int lane = j & 63, wid = j >> 6;

  __shared__ uint4 wlds[NCH_L * 1024];   // 144 KB
  __shared__ uint4 hpk4[32];             // 256 h as 128 packed-f16 dwords
  __shared__ float gates[1024];
  __shared__ float wpart[2][4];

  const uint4* wsrcl = (const uint4*)wlds_h + (size_t)dir * (NCH_L * 1024);
  for (int i = j; i < NCH_L * 1024; i += 1024) wlds[i] = wsrcl[i];
  if (j < 32) hpk4[j] = uint4{0, 0, 0, 0};
  __syncthreads();

  const float* xgbase =
      xg + (size_t)(dir * (BB * TT_LEN) + b * TT_LEN) * G4 + j;
  const uint4* wsb = wstr + (size_t)dir * (NCH_S * 1024) + j;
  float wo = (j < HH) ? w_out[dir * HH + j] : 0.0f;
  float cstate = 0.0f;

  int t0 = dir ? (TT_LEN - 1) : 0;
  float xg_next = xgbase[(size_t)t0 * G4];

#pragma unroll 1
  for (int s = 0; s < TT_LEN; ++s) {
    int t = dir ? (TT_LEN - 1 - s) : s;
    float acc = xg_next;
    if (s + 1 < TT_LEN) {
      int t2 = dir ? (TT_LEN - 2 - s) : (s + 1);
      xg_next = xgbase[(size_t)t2 * G4];
    }
    uint4 wbuf[8];
#pragma unroll
    for (int i = 0; i < 8; ++i) wbuf[i] = wsb[i * 1024];
#pragma unroll
    for (int c = 0; c < NCH_L; ++c) {
      uint4 w = wlds[c * 1024 + j];
      uint4 h = hpk4[c];
      acc = dot2acc(w.x, h.x, acc);
      acc = dot2acc(w.y, h.y, acc);
      acc = dot2acc(w.z, h.z, acc);
      acc = dot2acc(w.w, h.w, acc);
    }
#pragma unroll
    for (int g = 0; g < NCH_S; ++g) {
      uint4 w = wbuf[g & 7];
      if (g + 8 < NCH_S) wbuf[g & 7] = wsb[(g + 8) * 1024];
      uint4 h = hpk4[NCH_L + g];
      acc = dot2acc(w.x, h.x, acc);
      acc = dot2acc(w.y, h.y, acc);
      acc = dot2acc(w.z, h.z, acc);
      acc = dot2acc(w.w, h.w, acc);
    }
    gates[j] = acc;
    __syncthreads();

    if (j < HH) {
      float4 g4 = ((const float4*)gates)[j];
      float ig = sigm(g4.x);
      float fg = sigm(g4.y);
      float gg = tanhf(g4.z);
      float og = sigm(g4.w);
      cstate = fg * cstate + ig * gg;
      float h = og * tanhf(cstate);
      float prod = h * wo;
#pragma unroll
      for (int off = 32; off > 0; off >>= 1) prod += __shfl_down(prod, off, 64);
      if (lane == 0) wpart[s & 1][wid] = prod;
      float hn = __shfl_down(h, 1, 64);
      if (!(j & 1)) ((unsigned int*)hpk4)[j >> 1] = packh(h, hn);
    }
    __syncthreads();
    if (j == 0) {
      scores_part[(size_t)(dir * BB + b) * TT_LEN + t] =
          wpart[s & 1][0] + wpart[s & 1][1] + wpart[s & 1][2] + wpart[s & 1][3];
    }
  }
}

// ---------------- K3: u0 = (score_f + score_b + b_out) / TEMP --------------
__global__ void combine_scores(const float* __restrict__ scores_part,
                               const float* __restrict__ b_out,
                               float* __restrict__ u0) {
  int i = blockIdx.x * blockDim.x + threadIdx.x;
  if (i < BB * TT_LEN)
    u0[i] = (scores_part[i] + scores_part[BB * TT_LEN + i] + b_out[0]) * INV_TEMP;
}

// ---------------- K4: CRF forward-backward, single wave per batch ----------
// State c in 0..154 packed 3 slots/lane: c = slot*64 + lane. Shift c+/-1 via
// 3 shuffles + boundary selects. No LDS, no barriers. u0 row in 8 regs.
// ast rows at stride 160 (round-5 footprint); slot-2 global accesses are
// PREDICATED to l<27 (max offset 128+26=154 < 160 -> never leaves the row).
// All c budget-allowed (BUDGET=154=CMAX-1), so no allowed-mask needed.
__global__ __launch_bounds__(64) void dp2(const float* __restrict__ u0all,
                                          float* __restrict__ ast_g,
                                          float* __restrict__ out) {
  int b = blockIdx.x;
  int l = threadIdx.x;  // 0..63
  const float* u0 = u0all + b * TT_LEN;
  float* ast = ast_g + (size_t)b * TT_LEN * AST_STRIDE;

  float ur[8];
#pragma unroll
  for (int i = 0; i < 8; ++i) ur[i] = u0[i * 64 + l];

  int lm1 = (l + 63) & 63;
  int lp1 = (l + 1) & 63;

  float a0[3], a1[3];
  float u00 = __shfl(ur[0], 0, 64);
  a0[0] = (l == 1) ? (u00 + TRANS_T) : NEGF;
  a0[1] = NEGF;
  a0[2] = NEGF;
  a1[0] = (l == 0) ? 0.0f : NEGF;
  a1[1] = NEGF;
  a1[2] = NEGF;
  ast[l] = a0[0];
  ast[64 + l] = a0[1];
  if (l < 27) ast[128 + l] = a0[2];

  // ---- forward t = 1..511 ----
#pragma unroll
  for (int ch = 0; ch < 8; ++ch) {
    float uc = ur[ch];
#pragma unroll 1
    for (int tt = (ch == 0 ? 1 : 0); tt < 64; ++tt) {
      int t = ch * 64 + tt;
      float u0t = __shfl(uc, tt, 64);
      float w0a = __shfl(a0[0], lm1, 64);
      float w1a = __shfl(a0[1], lm1, 64);
      float w2a = __shfl(a0[2], lm1, 64);
      float w0b = __shfl(a1[0], lm1, 64);
      float w1b = __shfl(a1[1], lm1, 64);
      float w2b = __shfl(a1[2], lm1, 64);
      float p0a = (l == 0) ? NEGF : w0a;
      float p1a = (l == 0) ? w0a : w1a;
      float p2a = (l == 0) ? w1a : w2a;
      float p0b = (l == 0) ? NEGF : w0b;
      float p1b = (l == 0) ? w0b : w1b;
      float p2b = (l == 0) ? w1b : w2b;
      float n00 = u0t + la(p0a + TRANS_T, p0b);
      float n01 = u0t + la(p1a + TRANS_T, p1b);
      float n02 = u0t + la(p2a + TRANS_T, p2b);
      float n10 = la(a0[0], a1[0]);
      float n11 = la(a0[1], a1[1]);
      float n12 = la(a0[2], a1[2]);
      a0[0] = n00;
      a0[1] = n01;
      a0[2] = (l < 27) ? n02 : NEGF;
      a1[0] = n10;
      a1[1] = n11;
      a1[2] = (l < 27) ? n12 : NEGF;
      float* astr = ast + (size_t)t * AST_STRIDE;
      astr[l] = a0[0];
      astr[64 + l] = a0[1];
      if (l < 27) astr[128 + l] = a0[2];
    }
  }

  // ---- logZ ----
  float f00 = a0[0] + TRANS_T, f01 = a0[1] + TRANS_T, f02 = a0[2] + TRANS_T;
  float m = fmaxf(fmaxf(fmaxf(f00, f01), fmaxf(f02, a1[0])), fmaxf(a1[1], a1[2]));
#pragma unroll
  for (int off = 32; off > 0; off >>= 1) m = fmaxf(m, __shfl_xor(m, off, 64));
  float es = __expf(f00 - m) + __expf(f01 - m) + __expf(f02 - m) +
             __expf(a1[0] - m) + __expf(a1[1] - m) + __expf(a1[2] - m);
#pragma unroll
  for (int off = 32; off > 0; off >>= 1) es += __shfl_xor(es, off, 64);
  float lz = m + __logf(es);

  // ---- backward init (t = 511): beta0 = TRANS_T, beta1 = 0 (all allowed) --
  float b0[3], b1[3];
  b0[0] = TRANS_T;
  b0[1] = TRANS_T;
  b0[2] = (l < 27) ? TRANS_T : NEGF;
  b1[0] = 0.0f;
  b1[1] = 0.0f;
  b1[2] = (l < 27) ? 0.0f : NEGF;
  {
    float ts = __expf(a0[0] + TRANS_T - lz) + __expf(a0[1] + TRANS_T - lz) +
               ((l < 27) ? __expf(a0[2] + TRANS_T - lz) : 0.0f);
#pragma unroll
    for (int off = 32; off > 0; off >>= 1) ts += __shfl_xor(ts, off, 64);
    if (l == 0) out[b * TT_LEN + (TT_LEN - 1)] = ts;
  }

  // prefetch ast row 510
  float nr0 = ast[(size_t)510 * AST_STRIDE + l];
  float nr1 = ast[(size_t)510 * AST_STRIDE + 64 + l];
  float nr2 = (l < 27) ? ast[(size_t)510 * AST_STRIDE + 128 + l] : NEGF;

  // ---- backward t = 511..1 ----
#pragma unroll
  for (int ch = 7; ch >= 0; --ch) {
    float uc = ur[ch];
#pragma unroll 1
    for (int tt = 63; tt >= (ch == 0 ? 1 : 0); --tt) {
      int t = ch * 64 + tt;
      float u0t = __shfl(uc, tt, 64);
      float c0 = nr0, c1 = nr1, c2 = nr2;
      if (t >= 2) {
        const float* astr = ast + (size_t)(t - 2) * AST_STRIDE;
        nr0 = astr[l];
        nr1 = astr[64 + l];
        nr2 = (l < 27) ? astr[128 + l] : NEGF;
      }
      float w0 = __shfl(b0[0], lp1, 64);
      float w1 = __shfl(b0[1], lp1, 64);
      float w2 = __shfl(b0[2], lp1, 64);
      float x2 = (l == 63) ? NEGF : w2;
      float x1 = (l == 63) ? w2 : w1;
      float x0 = (l == 63) ? w1 : w0;
      float nb00 = la(u0t + TRANS_T + x0, b1[0]);
      float nb01 = la(u0t + TRANS_T + x1, b1[1]);
      float nb02 = la(u0t + TRANS_T + x2, b1[2]);
      float nb10 = la(u0t + x0, b1[0]);
      float nb11 = la(u0t + x1, b1[1]);
      float nb12 = la(u0t + x2, b1[2]);
      float tm = __expf(c0 + nb00 - lz) + __expf(c1 + nb01 - lz) +
                 ((l < 27) ? __expf(c2 + nb02 - lz) : 0.0f);
#pragma unroll
      for (int off = 32; off > 0; off >>= 1) tm += __shfl_xor(tm, off, 64);
      if (l == 0) out[b * TT_LEN + (t - 1)] = tm;
      b0[0] = nb00;
      b0[1] = nb01;
      b0[2] = (l < 27) ? nb02 : NEGF;
      b1[0] = nb10;
      b1[1] = nb11;
      b1[2] = (l < 27) ? nb12 : NEGF;
    }
  }
}

// ---------------------------------------------------------------------------
extern "C" void kernel_launch(void* const* d_in, const int* in_sizes, int n_in,
                              void* d_out, int out_size, void* d_ws, size_t ws_size,
                              hipStream_t stream) {
  const int* x = (const int*)d_in[0];
  const float* embed = (const float*)d_in[3];
  const float* wi_f = (const float*)d_in[4];
  const float* wh_f = (const float*)d_in[5];
  const float* bf = (const float*)d_in[6];
  const float* wi_b = (const float*)d_in[7];
  const float* wh_b = (const float*)d_in[8];
  const float* bbias = (const float*)d_in[9];
  const float* w_out = (const float*)d_in[10];
  const float* b_out = (const float*)d_in[11];

  float* ws = (float*)d_ws;
  float* b_p = ws;                                      // 2*1024 f32
  unsigned int* wlds_h = (unsigned int*)(b_p + 2 * G4); // 2*9*4096 dwords
  unsigned int* wstr_h = wlds_h + 2 * NCH_L * 4096;     // 2*23*4096 dwords
  _Float16* wi_t = (_Float16*)(wstr_h + 2 * NCH_S * 4096);  // 2*1024*320 f16
  _Float16* emb_h = wi_t + (size_t)2 * G4 * KPAD;       // 16384*320 f16
  float* xg = (float*)(emb_h + (size_t)BB * TT_LEN * KPAD);  // 2*16384*1024 f32
  float* scores_part = xg + (size_t)2 * BB * TT_LEN * G4;    // 2*16384
  float* u0 = scores_part + 2 * BB * TT_LEN;            // 16384
  float* ast_g = u0 + BB * TT_LEN;                      // 32*512*160 f32
  float* outp = (float*)d_out;

  prep_weights<<<256, 256, 0, stream>>>(wi_f, wi_b, wh_f, wh_b, bf, bbias,
                                        wi_t, b_p, wlds_h, wstr_h);
  gather_emb<<<BB * TT_LEN, 256, 0, stream>>>(x, embed, emb_h);
  dim3 g1(G4 / 64, (BB * TT_LEN) / 64, 2);
  xg_mfma<<<g1, 256, 0, stream>>>(emb_h, wi_t, b_p, xg);
  lstm_hyb<<<64, 1024, 0, stream>>>(xg, wlds_h, (const uint4*)wstr_h, w_out,
                                    scores_part);
  combine_scores<<<(BB * TT_LEN + 255) / 256, 256, 0, stream>>>(scores_part, b_out, u0);
  dp2<<<BB, 64, 0, stream>>>(u0, ast_g, outp);
}

// Round 8
// 1899.897 us; speedup vs baseline: 3.9644x; 1.0369x over previous
//
#include <hip/hip_runtime.h>
#include <math.h>

// Problem constants (reference: B,T,V,E,H = 32,512,32000,300,256)
#define BB 32
#define TT_LEN 512
#define EE 300
#define KPAD 320         // EE padded to multiple of 32 for MFMA K
#define HH 256
#define G4 1024          // 4*H
#define CMAX 155         // int(round(0.3*512))+1
#define TRANS_T 10.0f    // TRANSITION/TEMP
#define NEGF -1.0e9f
#define INV_TEMP 100.0f  // 1/TEMP
#define AST_STRIDE 160   // slot-2 accesses predicated l<27

// lstm weight split: LDS part = 8 uint4-chunks (k<64, 128 KB), register part
// = 24 uint4-chunks (k=64..255, 96 VGPR/col). Each uint4 = 8 f16 k-values
// for one gate column. Footprint identical to round-7 (one chunk moved
// LDS->stream).
#define NCH_L2 8
#define NREG 24

typedef _Float16 half2v __attribute__((ext_vector_type(2)));
typedef _Float16 half8 __attribute__((ext_vector_type(8)));
typedef float f32x4 __attribute__((ext_vector_type(4)));

__device__ __forceinline__ float la(float x, float y) {
  float m = fmaxf(x, y);
  float d = fminf(x, y) - m;
  return m + __logf(1.0f + __expf(d));
}

__device__ __forceinline__ float sigm(float x) {
  return 1.0f / (1.0f + __expf(-x));
}

__device__ __forceinline__ float dot2acc(unsigned int wd, unsigned int hd, float acc) {
#if __has_builtin(__builtin_amdgcn_fdot2)
  return __builtin_amdgcn_fdot2(__builtin_bit_cast(half2v, wd),
                                __builtin_bit_cast(half2v, hd), acc, false);
#else
  half2v a = __builtin_bit_cast(half2v, wd);
  half2v b = __builtin_bit_cast(half2v, hd);
  return acc + (float)a.x * (float)b.x + (float)a.y * (float)b.y;
#endif
}

__device__ __forceinline__ unsigned int packh(float a, float b) {
  half2v hp;
  hp.x = (_Float16)a;
  hp.y = (_Float16)b;
  return __builtin_bit_cast(unsigned int, hp);
}

// ---------------- K0: weight prep ------------------------------------------
// wi_t: f16 [dir][j'][k], j' = u*4+g, k padded to KPAD (zeros k>=300).
// wh packed f16 dwords (dword = k-pair (2k,2k+1) of gate column j):
//   LDS part  wlds_h: idx ((dir*NCH_L2 + c)*1024 + j)*4 + d, k0 = 8c+2d
//   reg part  wstr_h: idx ((dir*NREG + g)*1024 + j)*4 + d, k0 = 64+8g+2d
__global__ void prep_weights(const float* wi_f, const float* wi_b,
                             const float* wh_f, const float* wh_b,
                             const float* b_f, const float* b_b,
                             _Float16* wi_t, float* b_p,
                             unsigned int* wlds_h, unsigned int* wstr_h) {
  int idx = blockIdx.x * blockDim.x + threadIdx.x;
  int stride = gridDim.x * blockDim.x;
  // wi transpose: 2 * 1024 * KPAD f16
  for (int i = idx; i < 2 * G4 * KPAD; i += stride) {
    int dir = i / (G4 * KPAD);
    int r = i % (G4 * KPAD);
    int j = r / KPAD;
    int k = r % KPAD;
    int g = j & 3, u = j >> 2;
    const float* src = dir ? wi_b : wi_f;
    wi_t[i] = (k < EE) ? (_Float16)src[(size_t)k * G4 + g * HH + u] : (_Float16)0.0f;
  }
  // LDS-part dwords: 2 * NCH_L2 * 1024 * 4
  for (int i = idx; i < 2 * NCH_L2 * 4096; i += stride) {
    int dir = i / (NCH_L2 * 4096);
    int r = i % (NCH_L2 * 4096);
    int c = r / 4096;
    int r2 = r % 4096;
    int j = r2 >> 2, d = r2 & 3;
    int g = j & 3, u = j >> 2;
    int k0 = 8 * c + 2 * d;
    const float* src = dir ? wh_b : wh_f;
    wlds_h[i] = packh(src[k0 * G4 + g * HH + u], src[(k0 + 1) * G4 + g * HH + u]);
  }
  // register-part dwords: 2 * NREG * 1024 * 4
  for (int i = idx; i < 2 * NREG * 4096; i += stride) {
    int dir = i / (NREG * 4096);
    int r = i % (NREG * 4096);
    int gch = r / 4096;
    int r2 = r % 4096;
    int j = r2 >> 2, d = r2 & 3;
    int g = j & 3, u = j >> 2;
    int k0 = 64 + 8 * gch + 2 * d;
    const float* src = dir ? wh_b : wh_f;
    wstr_h[i] = packh(src[k0 * G4 + g * HH + u], src[(k0 + 1) * G4 + g * HH + u]);
  }
  for (int i = idx; i < 2 * G4; i += stride) {
    int dir = i / G4;
    int j = i % G4;
    int g = j & 3, u = j >> 2;
    const float* src = dir ? b_b : b_f;
    b_p[i] = src[g * HH + u];
  }
}

// ---------------- K_emb: gather embedding rows -> f16 dense (B*T, KPAD) ----
__global__ void gather_emb(const int* x, const float* embed, _Float16* emb_h) {
  int row = blockIdx.x;
  int v = x[row];
  const float* src = embed + (size_t)v * EE;
  _Float16* dst = emb_h + (size_t)row * KPAD;
  for (int k = threadIdx.x; k < KPAD; k += blockDim.x)
    dst[k] = (k < EE) ? (_Float16)src[k] : (_Float16)0.0f;
}

// ---------------- K1: xg = emb_h @ wi_t^T + b_p  (f16 MFMA) ----------------
__global__ __launch_bounds__(256) void xg_mfma(
    const _Float16* __restrict__ emb_h, const _Float16* __restrict__ wi_t,
    const float* __restrict__ b_p, float* __restrict__ xg) {
  int dir = blockIdx.z;
  int n0 = blockIdx.x * 64;
  int m0 = blockIdx.y * 64;
  int wave = threadIdx.x >> 6;
  int lane = threadIdx.x & 63;
  int l15 = lane & 15, quad = lane >> 4;

  const _Float16* arow = emb_h + (size_t)(m0 + wave * 16 + l15) * KPAD + quad * 8;
  const _Float16* bbase =
      wi_t + ((size_t)dir * G4 + n0 + l15) * KPAD + quad * 8;

  f32x4 acc[4];
#pragma unroll
  for (int nt = 0; nt < 4; ++nt) acc[nt] = (f32x4){0.f, 0.f, 0.f, 0.f};

#pragma unroll
  for (int kk = 0; kk < KPAD / 32; ++kk) {
    half8 a = *(const half8*)(arow + kk * 32);
#pragma unroll
    for (int nt = 0; nt < 4; ++nt) {
      half8 b = *(const half8*)(bbase + (size_t)nt * 16 * KPAD + kk * 32);
      acc[nt] = __builtin_amdgcn_mfma_f32_16x16x32_f16(a, b, acc[nt], 0, 0, 0);
    }
  }
#pragma unroll
  for (int nt = 0; nt < 4; ++nt) {
    int n = n0 + nt * 16 + l15;
    float bias = b_p[dir * G4 + n];
#pragma unroll
    for (int r = 0; r < 4; ++r) {
      int m = m0 + wave * 16 + quad * 4 + r;
      xg[((size_t)dir * (BB * TT_LEN) + m) * G4 + n] = acc[nt][r] + bias;
    }
  }
}

// ---------------- K2: LSTM recurrence, weights fully on-chip ---------------
// 64 blocks (dir,b), 512 threads (8 waves, 2/SIMD). Thread t owns gate
// columns t and t+512. Weights: k<64 in LDS (128 KB, staged once); k=64..255
// in registers (2 cols x 24 uint4 = 192 VGPR). Per step: zero off-chip
// weight traffic; LDS w-reads 131 KB (~1024 cy) overlap 512 dot2/thread
// VALU issue. h (256 f16) broadcast from LDS.
__global__ __launch_bounds__(512, 2) void lstm_reg(
    const float* __restrict__ xg, const unsigned int* __restrict__ wlds_h,
    const uint4* __restrict__ wstr, const float* __restrict__ w_out,
    float* __restrict__ scores_part) {
  int bid = blockIdx.x;            // 64 blocks: dir*32 + b
  int dir = bid >> 5, b = bid & 31;
  int t = threadIdx.x;             // 0..511
  int lane = t & 63, wid = t >> 6;

  __shared__ uint4 wlds[NCH_L2 * 1024];  // 128 KB
  __shared__ uint4 hpk4[32];             // 256 h as 128 packed-f16 dwords
  __shared__ float gates[1024];
  __shared__ float wpart[2][4];

  // stage LDS weight part (contiguous 128 KB per dir)
  const uint4* wsrcl = (const uint4*)wlds_h + (size_t)dir * (NCH_L2 * 1024);
  for (int i = t; i < NCH_L2 * 1024; i += 512) wlds[i] = wsrcl[i];
  // load register weight part (coalesced per wave)
  const uint4* wsb = wstr + (size_t)dir * (NREG * 1024);
  uint4 wr0[NREG], wr1[NREG];
#pragma unroll
  for (int g = 0; g < NREG; ++g) {
    wr0[g] = wsb[g * 1024 + t];
    wr1[g] = wsb[g * 1024 + t + 512];
  }
  if (t < 32) hpk4[t] = uint4{0, 0, 0, 0};
  __syncthreads();

  const float* xgbase =
      xg + (size_t)(dir * (BB * TT_LEN) + b * TT_LEN) * G4 + t;
  float wo = (t < HH) ? w_out[dir * HH + t] : 0.0f;
  float cstate = 0.0f;

  int t0 = dir ? (TT_LEN - 1) : 0;
  float xgn0 = xgbase[(size_t)t0 * G4];
  float xgn1 = xgbase[(size_t)t0 * G4 + 512];

#pragma unroll 1
  for (int s = 0; s < TT_LEN; ++s) {
    int tt = dir ? (TT_LEN - 1 - s) : s;
    float acc0 = xgn0, acc1 = xgn1;
    if (s + 1 < TT_LEN) {
      int t2 = dir ? (TT_LEN - 2 - s) : (s + 1);
      xgn0 = xgbase[(size_t)t2 * G4];
      xgn1 = xgbase[(size_t)t2 * G4 + 512];
    }
    // LDS-resident part: k < 64
#pragma unroll
    for (int c = 0; c < NCH_L2; ++c) {
      uint4 h = hpk4[c];
      uint4 w0 = wlds[c * 1024 + t];
      uint4 w1 = wlds[c * 1024 + 512 + t];
      acc0 = dot2acc(w0.x, h.x, acc0);
      acc0 = dot2acc(w0.y, h.y, acc0);
      acc0 = dot2acc(w0.z, h.z, acc0);
      acc0 = dot2acc(w0.w, h.w, acc0);
      acc1 = dot2acc(w1.x, h.x, acc1);
      acc1 = dot2acc(w1.y, h.y, acc1);
      acc1 = dot2acc(w1.z, h.z, acc1);
      acc1 = dot2acc(w1.w, h.w, acc1);
    }
    // register part: k = 64..255
#pragma unroll
    for (int g = 0; g < NREG; ++g) {
      uint4 h = hpk4[NCH_L2 + g];
      acc0 = dot2acc(wr0[g].x, h.x, acc0);
      acc0 = dot2acc(wr0[g].y, h.y, acc0);
      acc0 = dot2acc(wr0[g].z, h.z, acc0);
      acc0 = dot2acc(wr0[g].w, h.w, acc0);
      acc1 = dot2acc(wr1[g].x, h.x, acc1);
      acc1 = dot2acc(wr1[g].y, h.y, acc1);
      acc1 = dot2acc(wr1[g].z, h.z, acc1);
      acc1 = dot2acc(wr1[g].w, h.w, acc1);
    }
    gates[t] = acc0;
    gates[512 + t] = acc1;
    __syncthreads();

    if (t < HH) {
      float4 g4 = ((const float4*)gates)[t];
      float ig = sigm(g4.x);
      float fg = sigm(g4.y);
      float gg = tanhf(g4.z);
      float og = sigm(g4.w);
      cstate = fg * cstate + ig * gg;
      float h = og * tanhf(cstate);
      float prod = h * wo;
#pragma unroll
      for (int off = 32; off > 0; off >>= 1) prod += __shfl_down(prod, off, 64);
      if (lane == 0) wpart[s & 1][wid] = prod;
      float hn = __shfl_down(h, 1, 64);
      if (!(t & 1)) ((unsigned int*)hpk4)[t >> 1] = packh(h, hn);
    }
    __syncthreads();
    if (t == 0) {
      scores_part[(size_t)(dir * BB + b) * TT_LEN + tt] =
          wpart[s & 1][0] + wpart[s & 1][1] + wpart[s & 1][2] + wpart[s & 1][3];
    }
  }
}

// ---------------- K4: CRF forward-backward, single wave per batch ----------
// Fused u0 = (score_f + score_b + b_out) * INV_TEMP at load. State c in
// 0..154 packed 3 slots/lane: c = slot*64 + lane. Shift c+/-1 via shuffles +
// boundary selects. ast rows at stride 160; slot-2 accesses predicated l<27.
__global__ __launch_bounds__(64) void dp2(const float* __restrict__ scores_part,
                                          const float* __restrict__ b_out,
                                          float* __restrict__ ast_g,
                                          float* __restrict__ out) {
  int b = blockIdx.x;
  int l = threadIdx.x;  // 0..63
  const float* spf = scores_part + (size_t)b * TT_LEN;
  const float* spb = scores_part + (size_t)(BB + b) * TT_LEN;
  float bo = b_out[0];
  float* ast = ast_g + (size_t)b * TT_LEN * AST_STRIDE;

  float ur[8];
#pragma unroll
  for (int i = 0; i < 8; ++i)
    ur[i] = (spf[i * 64 + l] + spb[i * 64 + l] + bo) * INV_TEMP;

  int lm1 = (l + 63) & 63;
  int lp1 = (l + 1) & 63;

  float a0[3], a1[3];
  float u00 = __shfl(ur[0], 0, 64);
  a0[0] = (l == 1) ? (u00 + TRANS_T) : NEGF;
  a0[1] = NEGF;
  a0[2] = NEGF;
  a1[0] = (l == 0) ? 0.0f : NEGF;
  a1[1] = NEGF;
  a1[2] = NEGF;
  ast[l] = a0[0];
  ast[64 + l] = a0[1];
  if (l < 27) ast[128 + l] = a0[2];

  // ---- forward t = 1..511 ----
#pragma unroll
  for (int ch = 0; ch < 8; ++ch) {
    float uc = ur[ch];
#pragma unroll 1
    for (int tt = (ch == 0 ? 1 : 0); tt < 64; ++tt) {
      int t = ch * 64 + tt;
      float u0t = __shfl(uc, tt, 64);
      float w0a = __shfl(a0[0], lm1, 64);
      float w1a = __shfl(a0[1], lm1, 64);
      float w2a = __shfl(a0[2], lm1, 64);
      float w0b = __shfl(a1[0], lm1, 64);
      float w1b = __shfl(a1[1], lm1, 64);
      float w2b = __shfl(a1[2], lm1, 64);
      float p0a = (l == 0) ? NEGF : w0a;
      float p1a = (l == 0) ? w0a : w1a;
      float p2a = (l == 0) ? w1a : w2a;
      float p0b = (l == 0) ? NEGF : w0b;
      float p1b = (l == 0) ? w0b : w1b;
      float p2b = (l == 0) ? w1b : w2b;
      float n00 = u0t + la(p0a + TRANS_T, p0b);
      float n01 = u0t + la(p1a + TRANS_T, p1b);
      float n02 = u0t + la(p2a + TRANS_T, p2b);
      float n10 = la(a0[0], a1[0]);
      float n11 = la(a0[1], a1[1]);
      float n12 = la(a0[2], a1[2]);
      a0[0] = n00;
      a0[1] = n01;
      a0[2] = (l < 27) ? n02 : NEGF;
      a1[0] = n10;
      a1[1] = n11;
      a1[2] = (l < 27) ? n12 : NEGF;
      float* astr = ast + (size_t)t * AST_STRIDE;
      astr[l] = a0[0];
      astr[64 + l] = a0[1];
      if (l < 27) astr[128 + l] = a0[2];
    }
  }

  // ---- logZ ----
  float f00 = a0[0] + TRANS_T, f01 = a0[1] + TRANS_T, f02 = a0[2] + TRANS_T;
  float m = fmaxf(fmaxf(fmaxf(f00, f01), fmaxf(f02, a1[0])), fmaxf(a1[1], a1[2]));
#pragma unroll
  for (int off = 32; off > 0; off >>= 1) m = fmaxf(m, __shfl_xor(m, off, 64));
  float es = __expf(f00 - m) + __expf(f01 - m) + __expf(f02 - m) +
             __expf(a1[0] - m) + __expf(a1[1] - m) + __expf(a1[2] - m);
#pragma unroll
  for (int off = 32; off > 0; off >>= 1) es += __shfl_xor(es, off, 64);
  float lz = m + __logf(es);

  // ---- backward init (t = 511) ----
  float b0[3], b1[3];
  b0[0] = TRANS_T;
  b0[1] = TRANS_T;
  b0[2] = (l < 27) ? TRANS_T : NEGF;
  b1[0] = 0.0f;
  b1[1] = 0.0f;
  b1[2] = (l < 27) ? 0.0f : NEGF;
  {
    float ts = __expf(a0[0] + TRANS_T - lz) + __expf(a0[1] + TRANS_T - lz) +
               ((l < 27) ? __expf(a0[2] + TRANS_T - lz) : 0.0f);
#pragma unroll
    for (int off = 32; off > 0; off >>= 1) ts += __shfl_xor(ts, off, 64);
    if (l == 0) out[b * TT_LEN + (TT_LEN - 1)] = ts;
  }

  float nr0 = ast[(size_t)510 * AST_STRIDE + l];
  float nr1 = ast[(size_t)510 * AST_STRIDE + 64 + l];
  float nr2 = (l < 27) ? ast[(size_t)510 * AST_STRIDE + 128 + l] : NEGF;

  // ---- backward t = 511..1 ----
#pragma unroll
  for (int ch = 7; ch >= 0; --ch) {
    float uc = ur[ch];
#pragma unroll 1
    for (int tt = 63; tt >= (ch == 0 ? 1 : 0); --tt) {
      int t = ch * 64 + tt;
      float u0t = __shfl(uc, tt, 64);
      float c0 = nr0, c1 = nr1, c2 = nr2;
      if (t >= 2) {
        const float* astr = ast + (size_t)(t - 2) * AST_STRIDE;
        nr0 = astr[l];
        nr1 = astr[64 + l];
        nr2 = (l < 27) ? astr[128 + l] : NEGF;
      }
      float w0 = __shfl(b0[0], lp1, 64);
      float w1 = __shfl(b0[1], lp1, 64);
      float w2 = __shfl(b0[2], lp1, 64);
      float x2 = (l == 63) ? NEGF : w2;
      float x1 = (l == 63) ? w2 : w1;
      float x0 = (l == 63) ? w1 : w0;
      float nb00 = la(u0t + TRANS_T + x0, b1[0]);
      float nb01 = la(u0t + TRANS_T + x1, b1[1]);
      float nb02 = la(u0t + TRANS_T + x2, b1[2]);
      float nb10 = la(u0t + x0, b1[0]);
      float nb11 = la(u0t + x1, b1[1]);
      float nb12 = la(u0t + x2, b1[2]);
      float tm = __expf(c0 + nb00 - lz) + __expf(c1 + nb01 - lz) +
                 ((l < 27) ? __expf(c2 + nb02 - lz) : 0.0f);
#pragma unroll
      for (int off = 32; off > 0; off >>= 1) tm += __shfl_xor(tm, off, 64);
      if (l == 0) out[b * TT_LEN + (t - 1)] = tm;
      b0[0] = nb00;
      b0[1] = nb01;
      b0[2] = (l < 27) ? nb02 : NEGF;
      b1[0] = nb10;
      b1[1] = nb11;
      b1[2] = (l < 27) ? nb12 : NEGF;
    }
  }
}

// ---------------------------------------------------------------------------
extern "C" void kernel_launch(void* const* d_in, const int* in_sizes, int n_in,
                              void* d_out, int out_size, void* d_ws, size_t ws_size,
                              hipStream_t stream) {
  const int* x = (const int*)d_in[0];
  const float* embed = (const float*)d_in[3];
  const float* wi_f = (const float*)d_in[4];
  const float* wh_f = (const float*)d_in[5];
  const float* bf = (const float*)d_in[6];
  const float* wi_b = (const float*)d_in[7];
  const float* wh_b = (const float*)d_in[8];
  const float* bbias = (const float*)d_in[9];
  const float* w_out = (const float*)d_in[10];
  const float* b_out = (const float*)d_in[11];

  float* ws = (float*)d_ws;
  float* b_p = ws;                                      // 2*1024 f32
  unsigned int* wlds_h = (unsigned int*)(b_p + 2 * G4); // 2*8*4096 dwords
  unsigned int* wstr_h = wlds_h + 2 * NCH_L2 * 4096;    // 2*24*4096 dwords
  _Float16* wi_t = (_Float16*)(wstr_h + 2 * NREG * 4096);  // 2*1024*320 f16
  _Float16* emb_h = wi_t + (size_t)2 * G4 * KPAD;       // 16384*320 f16
  float* xg = (float*)(emb_h + (size_t)BB * TT_LEN * KPAD);  // 2*16384*1024 f32
  float* scores_part = xg + (size_t)2 * BB * TT_LEN * G4;    // 2*16384
  float* u0_unused = scores_part + 2 * BB * TT_LEN;     // 16384 (layout keep)
  float* ast_g = u0_unused + BB * TT_LEN;               // 32*512*160 f32
  float* outp = (float*)d_out;

  prep_weights<<<256, 256, 0, stream>>>(wi_f, wi_b, wh_f, wh_b, bf, bbias,
                                        wi_t, b_p, wlds_h, wstr_h);
  gather_emb<<<BB * TT_LEN, 256, 0, stream>>>(x, embed, emb_h);
  dim3 g1(G4 / 64, (BB * TT_LEN) / 64, 2);
  xg_mfma<<<g1, 256, 0, stream>>>(emb_h, wi_t, b_p, xg);
  lstm_reg<<<64, 512, 0, stream>>>(xg, wlds_h, (const uint4*)wstr_h, w_out,
                                   scores_part);
  dp2<<<BB, 64, 0, stream>>>(scores_part, b_out, ast_g, outp);
}